// Round 12
// baseline (116.735 us; speedup 1.0000x reference)
//
#include <hip/hip_runtime.h>
#include <hip/hip_bf16.h>
#include <math.h>

#define BATCH 8192

typedef __attribute__((ext_vector_type(8))) short bf16x8;
typedef __attribute__((ext_vector_type(4))) float f32x4;
typedef __attribute__((ext_vector_type(16))) float f32x16;

// 8B value with only 4B alignment guarantee -> ds_read2/ds_write2
struct u2a4 { unsigned int x, y; };

__device__ __forceinline__ unsigned short f2bf(float f) {
    unsigned int u = __builtin_bit_cast(unsigned int, f);
    u = (u + 0x7FFFu + ((u >> 16) & 1u)) >> 16;
    return (unsigned short)u;
}
__device__ __forceinline__ float bf2f(unsigned short h) {
    unsigned int u = ((unsigned int)h) << 16;
    return __builtin_bit_cast(float, u);
}
__device__ __forceinline__ unsigned int cvtpk(float a, float b) {
    unsigned int r;
    asm("v_cvt_pk_bf16_f32 %0, %1, %2" : "=v"(r) : "v"(a), "v"(b));
    return r;
}
__device__ __forceinline__ int swz(int i) { return i ^ ((i >> 3) & 3); }
__device__ __forceinline__ float relu_(float v) { return fmaxf(v, 0.f); }

// ---- weight fragment pack (ushorts) ----
#define W1OFF 0
#define W1FRAGS 4
#define W2OFF (W1OFF + W1FRAGS * 512)
#define W2FRAGS 6
#define W3OFF (W2OFF + W2FRAGS * 512)
#define W3FRAGS 18
#define CPACK_TOTAL (W3OFF + W3FRAGS * 512)
#define FC1_FRAGS (24 * 16)          // nb x ks, hi only
#define FC2_FRAGS (16 * 12)
#define FC1_TOTAL (FC1_FRAGS * 512)  // 196608
#define FC2_TOTAL (FC2_FRAGS * 512)  // 98304
#define ANG_TOTAL 112
#define PREP_TOTAL (CPACK_TOTAL + FC1_TOTAL + FC2_TOTAL + ANG_TOTAL)

// ---------------------------------------------------------------------------
__global__ __launch_bounds__(256) void prepack_kernel(
    const float* __restrict__ c1w, const float* __restrict__ c2w,
    const float* __restrict__ c3w, const float* __restrict__ f1w,
    const float* __restrict__ f2w, const float* __restrict__ qw,
    unsigned short* __restrict__ cpack, unsigned short* __restrict__ fpack1,
    unsigned short* __restrict__ fpack2, float* __restrict__ angtab)
{
    int e = blockIdx.x * 256 + threadIdx.x;
    if (e >= PREP_TOTAL) return;

    if (e < CPACK_TOTAL) {
        int f = e >> 9, r = e & 511;
        int l = r >> 3, j = r & 7;
        float w = 0.f; int hl = 0;
        if (f < W1FRAGS) {
            int sel = f >> 1; hl = f & 1;
            int oc = l & 15;
            int k = 8 * (l >> 4) + j;
            int ky, kx;
            if (sel == 0) { ky = k >> 3; kx = k & 7; }
            else          { ky = 4;      kx = k; }
            if (kx < 5 && ky < 5 && oc < 8) w = c1w[oc * 25 + ky * 5 + kx];
        } else if (f < W1FRAGS + W2FRAGS) {
            int f2 = f - W1FRAGS;
            int ky = f2 >> 1; hl = f2 & 1;
            int k = 8 * (l >> 4) + j;
            int kx = k >> 3, ic = k & 7, oc = l & 15;
            if (kx < 3) w = c2w[((oc * 8 + ic) * 3 + ky) * 3 + kx];
        } else {
            int f3 = f - W1FRAGS - W2FRAGS;      // (ky*3+kx)*2+hl
            int ky = f3 / 6, kx = (f3 / 2) % 3; hl = f3 & 1;
            int oc = l & 31, ic = 8 * (l >> 5) + j;
            w = c3w[((oc * 16 + ic) * 3 + ky) * 3 + kx];
        }
        unsigned short hv = f2bf(w);
        unsigned short lv = f2bf(w - bf2f(hv));
        cpack[e] = hl ? lv : hv;
        return;
    }
    e -= CPACK_TOTAL;
    if (e < FC1_TOTAL) {
        int phi = e >> 9, r = e & 511;
        int l = r >> 3, j = r & 7;
        int ks = phi & 15, nb = phi >> 4;
        int n = nb * 16 + (l & 15);
        int kg = ks * 32 + 8 * (l >> 4) + j;
        fpack1[e] = f2bf(f1w[n * 512 + kg]);
        return;
    }
    e -= FC1_TOTAL;
    if (e < FC2_TOTAL) {
        int phi = e >> 9, r = e & 511;
        int l = r >> 3, j = r & 7;
        int ks = phi % 12, nb = phi / 12;
        int n = nb * 16 + (l & 15);
        int kg = ks * 32 + 8 * (l >> 4) + j;
        fpack2[e] = f2bf(f2w[n * 384 + kg]);
        return;
    }
    e -= FC2_TOTAL;
    {
        int a = e >> 1;
        float th = 0.5f * qw[a];
        angtab[e] = (e & 1) ? sinf(th) : cosf(th);
    }
}

// ---------------------------------------------------------------------------
// Fused CNN (R8/R10 structure; conv1 unroll 8).
// ---------------------------------------------------------------------------
__global__ __launch_bounds__(256) void fused_cnn_mfma(
    const float* __restrict__ x,
    const float* __restrict__ c1b,
    const float* __restrict__ bn1g, const float* __restrict__ bn1b,
    const float* __restrict__ bn1m, const float* __restrict__ bn1v,
    const float* __restrict__ c2b,
    const float* __restrict__ bn2g, const float* __restrict__ bn2b,
    const float* __restrict__ bn2m, const float* __restrict__ bn2v,
    const float* __restrict__ c3b,
    const float* __restrict__ bn3g, const float* __restrict__ bn3b,
    const float* __restrict__ bn3m, const float* __restrict__ bn3v,
    const unsigned short* __restrict__ cpack,
    unsigned short* __restrict__ pooled_bf)
{
    __shared__ __align__(16) uint4 h1p4[1160];
    __shared__ __align__(16) unsigned int sd[2720];

    uint4* sbuf4 = (uint4*)sd;

    const int tid = threadIdx.x;
    const int lane = tid & 63;
    const int wv = tid >> 6;
    const int n = blockIdx.x;
    const int lrow = lane & 15;
    const int lq = lane >> 4;

    {
        const float4* xv = (const float4*)(x + (size_t)n * 4096);
        #pragma unroll
        for (int i = 0; i < 4; ++i) {
            int idx = tid + 256 * i;
            float4 v = xv[idx];
            int px = idx * 4;
            int y = px >> 6, xc = px & 63;
            int d = (y + 2) * 40 + (xc >> 1) + 1;
            u2a4 st; st.x = cvtpk(v.x, v.y); st.y = cvtpk(v.z, v.w);
            *(u2a4*)&sd[d] = st;
        }
        if (tid < 68)       { int r = tid / 34, c = tid % 34; sd[r * 40 + c] = 0u; }
        else if (tid < 136) { int u = tid - 68; int r = 66 + u / 34, c = u % 34; sd[r * 40 + c] = 0u; }
        if (tid < 128) { int r = 2 + (tid & 63); sd[r * 40 + ((tid >> 6) ? 33 : 0)] = 0u; }
        if (tid < 132) {
            int p;
            if (tid < 34) p = tid;
            else if (tid < 68) p = 33 * 34 + (tid - 34);
            else { int r = 1 + ((tid - 68) & 31); int side = (tid - 68) >> 5; p = r * 34 + side * 33; }
            h1p4[swz(p)] = (uint4){0u, 0u, 0u, 0u};
        }
    }
    __syncthreads();   // B1

    {
        bf16x8 wf0 = __builtin_bit_cast(bf16x8, *(const uint4*)(cpack + W1OFF + lane * 8));
        bf16x8 wf2 = __builtin_bit_cast(bf16x8, *(const uint4*)(cpack + W1OFF + 2 * 512 + lane * 8));
        float s1v[4], sh1v[4];
        #pragma unroll
        for (int r = 0; r < 4; ++r) {
            int oc = (4 * lq + r) & 7;
            s1v[r] = bn1g[oc] * rsqrtf(bn1v[oc] + 1e-5f);
            sh1v[r] = (c1b[oc] - bn1m[oc]) * s1v[r] + bn1b[oc];
        }
        #pragma unroll 8
        for (int t = 0; t < 16; ++t) {
            int oy = wv * 8 + (t >> 1), h = t & 1;
            int a1 = (2 * oy + lq) * 40 + 16 * h + lrow;
            u2a4 r1 = *(const u2a4*)&sd[a1];
            uint4 d1; d1.x = r1.x; d1.y = r1.y; d1.z = sd[a1 + 2]; d1.w = 0u;
            int a2 = (2 * oy + 4) * 40 + 16 * h + lrow;
            u2a4 r2 = *(const u2a4*)&sd[a2];
            uint4 d2; d2.x = r2.x; d2.y = r2.y; d2.z = sd[a2 + 2]; d2.w = 0u;
            f32x4 acc = {0.f, 0.f, 0.f, 0.f};
            acc = __builtin_amdgcn_mfma_f32_16x16x32_bf16(wf0, __builtin_bit_cast(bf16x8, d1), acc, 0, 0, 0);
            acc = __builtin_amdgcn_mfma_f32_16x16x32_bf16(wf2, __builtin_bit_cast(bf16x8, d2), acc, 0, 0, 0);
            if (lq < 2) {
                unsigned int u0 = cvtpk(fmaxf(fmaf(acc[0], s1v[0], sh1v[0]), 0.f),
                                        fmaxf(fmaf(acc[1], s1v[1], sh1v[1]), 0.f));
                unsigned int u1 = cvtpk(fmaxf(fmaf(acc[2], s1v[2], sh1v[2]), 0.f),
                                        fmaxf(fmaf(acc[3], s1v[3], sh1v[3]), 0.f));
                int p = (oy + 1) * 34 + 16 * h + lrow + 1;
                uint2 wr; wr.x = u0; wr.y = u1;
                *(uint2*)((char*)h1p4 + swz(p) * 16 + 8 * lq) = wr;
            }
        }
    }
    __syncthreads();   // B2

    {
        if (tid < 136) {
            int pp = tid >> 1, plane = tid & 1;
            int p;
            if (pp < 18) p = pp;
            else if (pp < 36) p = 17 * 18 + (pp - 18);
            else { int r = 1 + ((pp - 36) & 15); int side = (pp - 36) >> 4; p = r * 18 + side * 17; }
            sbuf4[plane * 324 + p] = (uint4){0u, 0u, 0u, 0u};
        }
        bf16x8 w2f[3];
        #pragma unroll
        for (int ky = 0; ky < 3; ++ky)
            w2f[ky] = __builtin_bit_cast(bf16x8,
                *(const uint4*)(cpack + W2OFF + (ky * 2) * 512 + lane * 8));
        float s2v[4], sh2v[4];
        #pragma unroll
        for (int r = 0; r < 4; ++r) {
            int oc = 4 * lq + r;
            s2v[r] = bn2g[oc] * rsqrtf(bn2v[oc] + 1e-5f);
            sh2v[r] = (c2b[oc] - bn2m[oc]) * s2v[r] + bn2b[oc];
        }
        int lqe = (lq == 3) ? 0 : lq;
        #pragma unroll
        for (int t = 0; t < 4; ++t) {
            int oy = 4 * wv + t;
            f32x4 acc = {0.f, 0.f, 0.f, 0.f};
            #pragma unroll
            for (int ky = 0; ky < 3; ++ky) {
                int iy = 2 * oy + ky;
                int p = iy * 34 + 2 * lrow + lqe;
                bf16x8 b = __builtin_bit_cast(bf16x8, h1p4[swz(p)]);
                acc = __builtin_amdgcn_mfma_f32_16x16x32_bf16(w2f[ky], b, acc, 0, 0, 0);
            }
            unsigned int u0 = cvtpk(fmaxf(fmaf(acc[0], s2v[0], sh2v[0]), 0.f),
                                    fmaxf(fmaf(acc[1], s2v[1], sh2v[1]), 0.f));
            unsigned int u1 = cvtpk(fmaxf(fmaf(acc[2], s2v[2], sh2v[2]), 0.f),
                                    fmaxf(fmaf(acc[3], s2v[3], sh2v[3]), 0.f));
            int p = (oy + 1) * 18 + lrow + 1;
            uint2 wr; wr.x = u0; wr.y = u1;
            *(uint2*)((char*)sbuf4 + ((lq >> 1) * 324 + p) * 16 + 8 * (lq & 1)) = wr;
        }
    }
    __syncthreads();   // B3

    {
        f32x16 accA = {0.f}, accB = {0.f};
        const int row = lane & 31;
        const int khalf = lane >> 5;
        const int kbase = khalf * 324;
        #pragma unroll
        for (int ky = 0; ky < 3; ++ky)
            #pragma unroll
            for (int kx = 0; kx < 3; ++kx) {
                int fb = (ky * 3 + kx) * 2;
                bf16x8 bh = __builtin_bit_cast(bf16x8, *(const uint4*)(cpack + W3OFF + fb * 512 + lane * 8));
                {
                    int pix = (4 * wv + 0 + (row >> 4) + ky) * 18 + (row & 15) + kx;
                    bf16x8 a = __builtin_bit_cast(bf16x8, sbuf4[kbase + pix]);
                    accA = __builtin_amdgcn_mfma_f32_32x32x16_bf16(a, bh, accA, 0, 0, 0);
                }
                {
                    int pix = (4 * wv + 2 + (row >> 4) + ky) * 18 + (row & 15) + kx;
                    bf16x8 a = __builtin_bit_cast(bf16x8, sbuf4[kbase + pix]);
                    accB = __builtin_amdgcn_mfma_f32_32x32x16_bf16(a, bh, accB, 0, 0, 0);
                }
            }
        int oc = lane & 31;
        float s3 = bn3g[oc] * rsqrtf(bn3v[oc] + 1e-5f);
        float sh3 = (c3b[oc] - bn3m[oc]) * s3 + bn3b[oc];
        float pool0 = 0.f, pool1 = 0.f;
        #pragma unroll
        for (int r = 0; r < 16; ++r) {
            float va = fmaxf(fmaf(accA[r], s3, sh3), 0.f);
            float vb = fmaxf(fmaf(accB[r], s3, sh3), 0.f);
            if (((r >> 2) & 1) == 0) { pool0 += va + vb; } else { pool1 += va + vb; }
        }
        int base = n * 512 + oc * 16 + wv * 4 + khalf;
        pooled_bf[base]     = (unsigned short)cvtpk(pool0 * (1.f / 16.f), 0.f);
        pooled_bf[base + 2] = (unsigned short)cvtpk(pool1 * (1.f / 16.f), 0.f);
    }
}

// ---------------------------------------------------------------------------
// Head: FC1 -> FC2 -> L2norm+qsim -> tail MLP. 8 samples/block, 1024 blocks,
// 18 KB LDS -> 8 blocks/CU. MFMA cols 8-15 are discarded duplicates (B-frag
// row = lr&7; epilogue writes guarded lr<8). 2 serial qsim iters per wave.
// ---------------------------------------------------------------------------
__global__ __launch_bounds__(256) void head_kernel(
    const unsigned short* __restrict__ pooled_bf,
    const unsigned short* __restrict__ fpack1,
    const unsigned short* __restrict__ fpack2,
    const float* __restrict__ f1b, const float* __restrict__ f2b,
    const float* __restrict__ angtab,
    const float* __restrict__ w1, const float* __restrict__ b1,
    const float* __restrict__ cg, const float* __restrict__ cb,
    const float* __restrict__ cm, const float* __restrict__ cv,
    const float* __restrict__ w2, const float* __restrict__ b2,
    const float* __restrict__ w3, const float* __restrict__ b3,
    const float* __restrict__ w4, const float* __restrict__ b4,
    float* __restrict__ out)
{
    __shared__ __align__(16) unsigned short As[4096];   // [8][512]
    __shared__ __align__(16) unsigned short h1[3072];   // [8][384]
    __shared__ __align__(16) unsigned short h2[2048];   // [8][256]

    const int tid = threadIdx.x;
    const int lane = tid & 63;
    const int w = tid >> 6;           // wave 0..3
    const int lr = lane & 15;
    const int lr8 = lr & 7;           // sample row (8-15 duplicate 0-7)
    const int lq = lane >> 4;
    const int m0 = blockIdx.x * 8;

    // ---- stage pooled[m0..m0+7][0..511] (coalesced) ----
    {
        const uint4* src = (const uint4*)(pooled_bf + (size_t)m0 * 512);
        #pragma unroll
        for (int i = 0; i < 2; ++i) {
            int q = i * 256 + tid;           // uint4 idx; row=q>>6, kc=q&63
            uint4 v = src[q];
            int row = q >> 6, kc = q & 63;
            int byte = (row * 1024 + 16 * kc) ^ ((row & 7) << 4);
            *(uint4*)((char*)As + byte) = v;
        }
    }
    __syncthreads();   // B1

    // ---- FC1: wave w covers n in [96w, 96w+96), 6 frags; K=512=16 ks ----
    {
        f32x4 acc[6];
        #pragma unroll
        for (int i = 0; i < 6; ++i) acc[i] = (f32x4){0.f, 0.f, 0.f, 0.f};
        for (int ks = 0; ks < 16; ++ks) {
            int byte = (lr8 * 1024 + 16 * (ks * 4 + lq)) ^ (lr8 << 4);
            bf16x8 act = __builtin_bit_cast(bf16x8, *(const uint4*)((char*)As + byte));
            #pragma unroll
            for (int nf = 0; nf < 6; ++nf) {
                int nb = 6 * w + nf;
                bf16x8 wf = __builtin_bit_cast(bf16x8,
                    *(const uint4*)(fpack1 + (size_t)(nb * 16 + ks) * 512 + lane * 8));
                acc[nf] = __builtin_amdgcn_mfma_f32_16x16x32_bf16(wf, act, acc[nf], 0, 0, 0);
            }
        }
        if (lr < 8) {
            #pragma unroll
            for (int nf = 0; nf < 6; ++nf) {
                int n0 = 96 * w + 16 * nf + 4 * lq;
                float4 bb = *(const float4*)(f1b + n0);
                unsigned int u0 = cvtpk(relu_(acc[nf][0] + bb.x), relu_(acc[nf][1] + bb.y));
                unsigned int u1 = cvtpk(relu_(acc[nf][2] + bb.z), relu_(acc[nf][3] + bb.w));
                int byte = (lr * 768 + 2 * n0) ^ (lr << 4);
                uint2 wr; wr.x = u0; wr.y = u1;
                *(uint2*)((char*)h1 + byte) = wr;
            }
        }
    }
    __syncthreads();   // B2

    // ---- FC2: wave w covers n in [64w, 64w+64), 4 frags; K=384=12 ks ----
    {
        f32x4 acc[4];
        #pragma unroll
        for (int i = 0; i < 4; ++i) acc[i] = (f32x4){0.f, 0.f, 0.f, 0.f};
        for (int ks = 0; ks < 12; ++ks) {
            int byte = (lr8 * 768 + 16 * (ks * 4 + lq)) ^ (lr8 << 4);
            bf16x8 act = __builtin_bit_cast(bf16x8, *(const uint4*)((char*)h1 + byte));
            #pragma unroll
            for (int nf = 0; nf < 4; ++nf) {
                int nb = 4 * w + nf;
                bf16x8 wf = __builtin_bit_cast(bf16x8,
                    *(const uint4*)(fpack2 + (size_t)(nb * 12 + ks) * 512 + lane * 8));
                acc[nf] = __builtin_amdgcn_mfma_f32_16x16x32_bf16(wf, act, acc[nf], 0, 0, 0);
            }
        }
        if (lr < 8) {
            #pragma unroll
            for (int nf = 0; nf < 4; ++nf) {
                int n0 = 64 * w + 16 * nf + 4 * lq;
                float4 bb = *(const float4*)(f2b + n0);
                unsigned int u0 = cvtpk(relu_(acc[nf][0] + bb.x), relu_(acc[nf][1] + bb.y));
                unsigned int u1 = cvtpk(relu_(acc[nf][2] + bb.z), relu_(acc[nf][3] + bb.w));
                int byte = (lr * 512 + 2 * n0) ^ (lr << 3);
                uint2 wr; wr.x = u0; wr.y = u1;
                *(uint2*)((char*)h2 + byte) = wr;
            }
        }
    }
    __syncthreads();   // B3

    // ---- qsim + tail, 2 samples per wave ----
    const int csrc = lane ^ ((lane >> 1) & 31);
    for (int it = 0; it < 2; ++it) {
        int m = w * 2 + it;
        int byte = (m * 512 + 8 * lane) ^ (m << 3);
        uint2 fv = *(const uint2*)((char*)h2 + byte);
        float a0 = bf2f((unsigned short)(fv.x & 0xffff));
        float a1 = bf2f((unsigned short)(fv.x >> 16));
        float a2 = bf2f((unsigned short)(fv.y & 0xffff));
        float a3 = bf2f((unsigned short)(fv.y >> 16));

        float ss = a0 * a0 + a1 * a1 + a2 * a2 + a3 * a3;
        #pragma unroll
        for (int mm = 32; mm; mm >>= 1) ss += __shfl_xor(ss, mm);
        float inv = 1.f / fmaxf(sqrtf(ss), 1e-12f);
        a0 *= inv; a1 *= inv; a2 *= inv; a3 *= inv;

        for (int l = 0; l < 7; ++l) {
            #pragma unroll
            for (int q = 0; q < 6; ++q) {
                float cs = angtab[(l * 8 + q) * 2], sn = angtab[(l * 8 + q) * 2 + 1];
                int mask = 32 >> q;
                float sg = (lane & mask) ? sn : -sn;
                float b0 = __shfl_xor(a0, mask), b1v = __shfl_xor(a1, mask);
                float b2v = __shfl_xor(a2, mask), b3v = __shfl_xor(a3, mask);
                a0 = fmaf(sg, b0, cs * a0); a1 = fmaf(sg, b1v, cs * a1);
                a2 = fmaf(sg, b2v, cs * a2); a3 = fmaf(sg, b3v, cs * a3);
            }
            {
                float cs = angtab[(l * 8 + 6) * 2], sn = angtab[(l * 8 + 6) * 2 + 1];
                float n0 = cs * a0 - sn * a2, n2 = fmaf(sn, a0, cs * a2);
                float n1 = cs * a1 - sn * a3, n3 = fmaf(sn, a1, cs * a3);
                a0 = n0; a1 = n1; a2 = n2; a3 = n3;
            }
            {
                float cs = angtab[(l * 8 + 7) * 2], sn = angtab[(l * 8 + 7) * 2 + 1];
                float n0 = cs * a0 - sn * a1, n1 = fmaf(sn, a0, cs * a1);
                float n2 = cs * a2 - sn * a3, n3 = fmaf(sn, a2, cs * a3);
                a0 = n0; a1 = n1; a2 = n2; a3 = n3;
            }
            a0 = __shfl(a0, csrc); a1 = __shfl(a1, csrc);
            a2 = __shfl(a2, csrc); a3 = __shfl(a3, csrc);
            {
                bool f = (lane & 1);
                float n0 = f ? a2 : a0, n2 = f ? a0 : a2;
                float n1 = f ? a3 : a1, n3 = f ? a1 : a3;
                a0 = n0; a1 = n1; a2 = n2; a3 = n3;
            }
            { float t = a2; a2 = a3; a3 = t; }
        }

        float part = a0 * a0 + a1 * a1 + a2 * a2 + a3 * a3;
        part = (lane & 32) ? -part : part;
        #pragma unroll
        for (int mm = 32; mm; mm >>= 1) part += __shfl_xor(part, mm);
        float qv = part;

        float z = fmaxf(fmaf(qv, w1[lane], b1[lane]), 0.f);
        z = fmaf(z - cm[lane], cg[lane] * rsqrtf(cv[lane] + 1e-5f), cb[lane]);
        {
            int j = lane & 31, hb = lane & 32;
            float acc = 0.f;
            #pragma unroll
            for (int t = 0; t < 32; ++t)
                acc = fmaf(w2[j * 64 + hb + t], __shfl(z, hb + t), acc);
            acc += __shfl_xor(acc, 32);
            z = fmaxf(acc + b2[j], 0.f);
        }
        {
            int j3 = lane & 15, qh = (lane >> 4) & 3;
            float p = 0.f;
            #pragma unroll
            for (int t = 0; t < 8; ++t)
                p = fmaf(w3[j3 * 32 + 8 * qh + t], __shfl(z, 8 * qh + t), p);
            p += __shfl_xor(p, 16);
            p += __shfl_xor(p, 32);
            z = fmaxf(p + b3[j3], 0.f);
        }
        {
            float t4 = w4[lane & 15] * z;
            t4 += __shfl_xor(t4, 1); t4 += __shfl_xor(t4, 2);
            t4 += __shfl_xor(t4, 4); t4 += __shfl_xor(t4, 8);
            float o = t4 + b4[0];
            if (lane == 0) out[m0 + m] = 1.f / (1.f + expf(-o));
        }
    }
}

// ---------------------------------------------------------------------------
extern "C" void kernel_launch(void* const* d_in, const int* in_sizes, int n_in,
                              void* d_out, int out_size, void* d_ws, size_t ws_size,
                              hipStream_t stream)
{
    const float* x    = (const float*)d_in[0];
    const float* c1w  = (const float*)d_in[1];
    const float* c1b  = (const float*)d_in[2];
    const float* bn1g = (const float*)d_in[3];
    const float* bn1b = (const float*)d_in[4];
    const float* bn1m = (const float*)d_in[5];
    const float* bn1v = (const float*)d_in[6];
    const float* c2w  = (const float*)d_in[7];
    const float* c2b  = (const float*)d_in[8];
    const float* bn2g = (const float*)d_in[9];
    const float* bn2b = (const float*)d_in[10];
    const float* bn2m = (const float*)d_in[11];
    const float* bn2v = (const float*)d_in[12];
    const float* c3w  = (const float*)d_in[13];
    const float* c3b  = (const float*)d_in[14];
    const float* bn3g = (const float*)d_in[15];
    const float* bn3b = (const float*)d_in[16];
    const float* bn3m = (const float*)d_in[17];
    const float* bn3v = (const float*)d_in[18];
    const float* f1w  = (const float*)d_in[19];
    const float* f1b  = (const float*)d_in[20];
    const float* f2w  = (const float*)d_in[21];
    const float* f2b  = (const float*)d_in[22];
    const float* qw   = (const float*)d_in[23];
    const float* w1   = (const float*)d_in[24];
    const float* b1   = (const float*)d_in[25];
    const float* cg   = (const float*)d_in[26];
    const float* cb   = (const float*)d_in[27];
    const float* cm   = (const float*)d_in[28];
    const float* cv   = (const float*)d_in[29];
    const float* w2   = (const float*)d_in[30];
    const float* b2   = (const float*)d_in[31];
    const float* w3   = (const float*)d_in[32];
    const float* b3   = (const float*)d_in[33];
    const float* w4   = (const float*)d_in[34];
    const float* b4   = (const float*)d_in[35];

    unsigned short* ws = (unsigned short*)d_ws;
    unsigned short* pooled_bf = ws;                              // 8192*512 ush
    unsigned short* cpack     = pooled_bf + (size_t)BATCH * 512;
    unsigned short* fpack1    = cpack + CPACK_TOTAL;
    unsigned short* fpack2    = fpack1 + FC1_TOTAL;
    float*          angtab    = (float*)(fpack2 + FC2_TOTAL);

    prepack_kernel<<<(PREP_TOTAL + 255) / 256, 256, 0, stream>>>(
        c1w, c2w, c3w, f1w, f2w, qw, cpack, fpack1, fpack2, angtab);

    fused_cnn_mfma<<<BATCH, 256, 0, stream>>>(
        x, c1b, bn1g, bn1b, bn1m, bn1v,
        c2b, bn2g, bn2b, bn2m, bn2v,
        c3b, bn3g, bn3b, bn3m, bn3v, cpack, pooled_bf);

    head_kernel<<<BATCH / 8, 256, 0, stream>>>(
        pooled_bf, fpack1, fpack2, f1b, f2b, angtab,
        w1, b1, cg, cb, cm, cv, w2, b2, w3, b3, w4, b4, (float*)d_out);
}

// Round 13
// 112.719 us; speedup vs baseline: 1.0356x; 1.0356x over previous
//
#include <hip/hip_runtime.h>
#include <hip/hip_bf16.h>
#include <math.h>

#define BATCH 8192

typedef __attribute__((ext_vector_type(8))) short bf16x8;
typedef __attribute__((ext_vector_type(4))) float f32x4;
typedef __attribute__((ext_vector_type(16))) float f32x16;

// 8B value with only 4B alignment guarantee -> ds_read2/ds_write2
struct u2a4 { unsigned int x, y; };

__device__ __forceinline__ unsigned short f2bf(float f) {
    unsigned int u = __builtin_bit_cast(unsigned int, f);
    u = (u + 0x7FFFu + ((u >> 16) & 1u)) >> 16;
    return (unsigned short)u;
}
__device__ __forceinline__ float bf2f(unsigned short h) {
    unsigned int u = ((unsigned int)h) << 16;
    return __builtin_bit_cast(float, u);
}
__device__ __forceinline__ unsigned int cvtpk(float a, float b) {
    unsigned int r;
    asm("v_cvt_pk_bf16_f32 %0, %1, %2" : "=v"(r) : "v"(a), "v"(b));
    return r;
}
__device__ __forceinline__ int swz(int i) { return i ^ ((i >> 3) & 3); }
__device__ __forceinline__ float relu_(float v) { return fmaxf(v, 0.f); }

// ---- weight fragment pack (ushorts) ----
#define W1OFF 0
#define W1FRAGS 4
#define W2OFF (W1OFF + W1FRAGS * 512)
#define W2FRAGS 6
#define W3OFF (W2OFF + W2FRAGS * 512)
#define W3FRAGS 18
#define CPACK_TOTAL (W3OFF + W3FRAGS * 512)
#define FC1_FRAGS (24 * 16)          // nb x ks, hi only
#define FC2_FRAGS (16 * 12)
#define FC1_TOTAL (FC1_FRAGS * 512)  // 196608
#define FC2_TOTAL (FC2_FRAGS * 512)  // 98304
#define ANG_TOTAL 112
#define PREP_TOTAL (CPACK_TOTAL + FC1_TOTAL + FC2_TOTAL + ANG_TOTAL)

// ---------------------------------------------------------------------------
__global__ __launch_bounds__(256) void prepack_kernel(
    const float* __restrict__ c1w, const float* __restrict__ c2w,
    const float* __restrict__ c3w, const float* __restrict__ f1w,
    const float* __restrict__ f2w, const float* __restrict__ qw,
    unsigned short* __restrict__ cpack, unsigned short* __restrict__ fpack1,
    unsigned short* __restrict__ fpack2, float* __restrict__ angtab)
{
    int e = blockIdx.x * 256 + threadIdx.x;
    if (e >= PREP_TOTAL) return;

    if (e < CPACK_TOTAL) {
        int f = e >> 9, r = e & 511;
        int l = r >> 3, j = r & 7;
        float w = 0.f; int hl = 0;
        if (f < W1FRAGS) {
            int sel = f >> 1; hl = f & 1;
            int oc = l & 15;
            int k = 8 * (l >> 4) + j;
            int ky, kx;
            if (sel == 0) { ky = k >> 3; kx = k & 7; }
            else          { ky = 4;      kx = k; }
            if (kx < 5 && ky < 5 && oc < 8) w = c1w[oc * 25 + ky * 5 + kx];
        } else if (f < W1FRAGS + W2FRAGS) {
            int f2 = f - W1FRAGS;
            int ky = f2 >> 1; hl = f2 & 1;
            int k = 8 * (l >> 4) + j;
            int kx = k >> 3, ic = k & 7, oc = l & 15;
            if (kx < 3) w = c2w[((oc * 8 + ic) * 3 + ky) * 3 + kx];
        } else {
            int f3 = f - W1FRAGS - W2FRAGS;      // (ky*3+kx)*2+hl
            int ky = f3 / 6, kx = (f3 / 2) % 3; hl = f3 & 1;
            int oc = l & 31, ic = 8 * (l >> 5) + j;
            w = c3w[((oc * 16 + ic) * 3 + ky) * 3 + kx];
        }
        unsigned short hv = f2bf(w);
        unsigned short lv = f2bf(w - bf2f(hv));
        cpack[e] = hl ? lv : hv;
        return;
    }
    e -= CPACK_TOTAL;
    if (e < FC1_TOTAL) {
        int phi = e >> 9, r = e & 511;
        int l = r >> 3, j = r & 7;
        int ks = phi & 15, nb = phi >> 4;
        int n = nb * 16 + (l & 15);
        int kg = ks * 32 + 8 * (l >> 4) + j;
        fpack1[e] = f2bf(f1w[n * 512 + kg]);
        return;
    }
    e -= FC1_TOTAL;
    if (e < FC2_TOTAL) {
        int phi = e >> 9, r = e & 511;
        int l = r >> 3, j = r & 7;
        int ks = phi % 12, nb = phi / 12;
        int n = nb * 16 + (l & 15);
        int kg = ks * 32 + 8 * (l >> 4) + j;
        fpack2[e] = f2bf(f2w[n * 384 + kg]);
        return;
    }
    e -= FC2_TOTAL;
    {
        int a = e >> 1;
        float th = 0.5f * qw[a];
        angtab[e] = (e & 1) ? sinf(th) : cosf(th);
    }
}

// ---------------------------------------------------------------------------
// Fused CNN (R8/R10 structure).
// ---------------------------------------------------------------------------
__global__ __launch_bounds__(256) void fused_cnn_mfma(
    const float* __restrict__ x,
    const float* __restrict__ c1b,
    const float* __restrict__ bn1g, const float* __restrict__ bn1b,
    const float* __restrict__ bn1m, const float* __restrict__ bn1v,
    const float* __restrict__ c2b,
    const float* __restrict__ bn2g, const float* __restrict__ bn2b,
    const float* __restrict__ bn2m, const float* __restrict__ bn2v,
    const float* __restrict__ c3b,
    const float* __restrict__ bn3g, const float* __restrict__ bn3b,
    const float* __restrict__ bn3m, const float* __restrict__ bn3v,
    const unsigned short* __restrict__ cpack,
    unsigned short* __restrict__ pooled_bf)
{
    __shared__ __align__(16) uint4 h1p4[1160];
    __shared__ __align__(16) unsigned int sd[2720];

    uint4* sbuf4 = (uint4*)sd;

    const int tid = threadIdx.x;
    const int lane = tid & 63;
    const int wv = tid >> 6;
    const int n = blockIdx.x;
    const int lrow = lane & 15;
    const int lq = lane >> 4;

    {
        const float4* xv = (const float4*)(x + (size_t)n * 4096);
        #pragma unroll
        for (int i = 0; i < 4; ++i) {
            int idx = tid + 256 * i;
            float4 v = xv[idx];
            int px = idx * 4;
            int y = px >> 6, xc = px & 63;
            int d = (y + 2) * 40 + (xc >> 1) + 1;
            u2a4 st; st.x = cvtpk(v.x, v.y); st.y = cvtpk(v.z, v.w);
            *(u2a4*)&sd[d] = st;
        }
        if (tid < 68)       { int r = tid / 34, c = tid % 34; sd[r * 40 + c] = 0u; }
        else if (tid < 136) { int u = tid - 68; int r = 66 + u / 34, c = u % 34; sd[r * 40 + c] = 0u; }
        if (tid < 128) { int r = 2 + (tid & 63); sd[r * 40 + ((tid >> 6) ? 33 : 0)] = 0u; }
        if (tid < 132) {
            int p;
            if (tid < 34) p = tid;
            else if (tid < 68) p = 33 * 34 + (tid - 34);
            else { int r = 1 + ((tid - 68) & 31); int side = (tid - 68) >> 5; p = r * 34 + side * 33; }
            h1p4[swz(p)] = (uint4){0u, 0u, 0u, 0u};
        }
    }
    __syncthreads();   // B1

    {
        bf16x8 wf0 = __builtin_bit_cast(bf16x8, *(const uint4*)(cpack + W1OFF + lane * 8));
        bf16x8 wf2 = __builtin_bit_cast(bf16x8, *(const uint4*)(cpack + W1OFF + 2 * 512 + lane * 8));
        float s1v[4], sh1v[4];
        #pragma unroll
        for (int r = 0; r < 4; ++r) {
            int oc = (4 * lq + r) & 7;
            s1v[r] = bn1g[oc] * rsqrtf(bn1v[oc] + 1e-5f);
            sh1v[r] = (c1b[oc] - bn1m[oc]) * s1v[r] + bn1b[oc];
        }
        #pragma unroll 4
        for (int t = 0; t < 16; ++t) {
            int oy = wv * 8 + (t >> 1), h = t & 1;
            int a1 = (2 * oy + lq) * 40 + 16 * h + lrow;
            u2a4 r1 = *(const u2a4*)&sd[a1];
            uint4 d1; d1.x = r1.x; d1.y = r1.y; d1.z = sd[a1 + 2]; d1.w = 0u;
            int a2 = (2 * oy + 4) * 40 + 16 * h + lrow;
            u2a4 r2 = *(const u2a4*)&sd[a2];
            uint4 d2; d2.x = r2.x; d2.y = r2.y; d2.z = sd[a2 + 2]; d2.w = 0u;
            f32x4 acc = {0.f, 0.f, 0.f, 0.f};
            acc = __builtin_amdgcn_mfma_f32_16x16x32_bf16(wf0, __builtin_bit_cast(bf16x8, d1), acc, 0, 0, 0);
            acc = __builtin_amdgcn_mfma_f32_16x16x32_bf16(wf2, __builtin_bit_cast(bf16x8, d2), acc, 0, 0, 0);
            if (lq < 2) {
                unsigned int u0 = cvtpk(fmaxf(fmaf(acc[0], s1v[0], sh1v[0]), 0.f),
                                        fmaxf(fmaf(acc[1], s1v[1], sh1v[1]), 0.f));
                unsigned int u1 = cvtpk(fmaxf(fmaf(acc[2], s1v[2], sh1v[2]), 0.f),
                                        fmaxf(fmaf(acc[3], s1v[3], sh1v[3]), 0.f));
                int p = (oy + 1) * 34 + 16 * h + lrow + 1;
                uint2 wr; wr.x = u0; wr.y = u1;
                *(uint2*)((char*)h1p4 + swz(p) * 16 + 8 * lq) = wr;
            }
        }
    }
    __syncthreads();   // B2

    {
        if (tid < 136) {
            int pp = tid >> 1, plane = tid & 1;
            int p;
            if (pp < 18) p = pp;
            else if (pp < 36) p = 17 * 18 + (pp - 18);
            else { int r = 1 + ((pp - 36) & 15); int side = (pp - 36) >> 4; p = r * 18 + side * 17; }
            sbuf4[plane * 324 + p] = (uint4){0u, 0u, 0u, 0u};
        }
        bf16x8 w2f[3];
        #pragma unroll
        for (int ky = 0; ky < 3; ++ky)
            w2f[ky] = __builtin_bit_cast(bf16x8,
                *(const uint4*)(cpack + W2OFF + (ky * 2) * 512 + lane * 8));
        float s2v[4], sh2v[4];
        #pragma unroll
        for (int r = 0; r < 4; ++r) {
            int oc = 4 * lq + r;
            s2v[r] = bn2g[oc] * rsqrtf(bn2v[oc] + 1e-5f);
            sh2v[r] = (c2b[oc] - bn2m[oc]) * s2v[r] + bn2b[oc];
        }
        int lqe = (lq == 3) ? 0 : lq;
        #pragma unroll
        for (int t = 0; t < 4; ++t) {
            int oy = 4 * wv + t;
            f32x4 acc = {0.f, 0.f, 0.f, 0.f};
            #pragma unroll
            for (int ky = 0; ky < 3; ++ky) {
                int iy = 2 * oy + ky;
                int p = iy * 34 + 2 * lrow + lqe;
                bf16x8 b = __builtin_bit_cast(bf16x8, h1p4[swz(p)]);
                acc = __builtin_amdgcn_mfma_f32_16x16x32_bf16(w2f[ky], b, acc, 0, 0, 0);
            }
            unsigned int u0 = cvtpk(fmaxf(fmaf(acc[0], s2v[0], sh2v[0]), 0.f),
                                    fmaxf(fmaf(acc[1], s2v[1], sh2v[1]), 0.f));
            unsigned int u1 = cvtpk(fmaxf(fmaf(acc[2], s2v[2], sh2v[2]), 0.f),
                                    fmaxf(fmaf(acc[3], s2v[3], sh2v[3]), 0.f));
            int p = (oy + 1) * 18 + lrow + 1;
            uint2 wr; wr.x = u0; wr.y = u1;
            *(uint2*)((char*)sbuf4 + ((lq >> 1) * 324 + p) * 16 + 8 * (lq & 1)) = wr;
        }
    }
    __syncthreads();   // B3

    {
        f32x16 accA = {0.f}, accB = {0.f};
        const int row = lane & 31;
        const int khalf = lane >> 5;
        const int kbase = khalf * 324;
        #pragma unroll
        for (int ky = 0; ky < 3; ++ky)
            #pragma unroll
            for (int kx = 0; kx < 3; ++kx) {
                int fb = (ky * 3 + kx) * 2;
                bf16x8 bh = __builtin_bit_cast(bf16x8, *(const uint4*)(cpack + W3OFF + fb * 512 + lane * 8));
                {
                    int pix = (4 * wv + 0 + (row >> 4) + ky) * 18 + (row & 15) + kx;
                    bf16x8 a = __builtin_bit_cast(bf16x8, sbuf4[kbase + pix]);
                    accA = __builtin_amdgcn_mfma_f32_32x32x16_bf16(a, bh, accA, 0, 0, 0);
                }
                {
                    int pix = (4 * wv + 2 + (row >> 4) + ky) * 18 + (row & 15) + kx;
                    bf16x8 a = __builtin_bit_cast(bf16x8, sbuf4[kbase + pix]);
                    accB = __builtin_amdgcn_mfma_f32_32x32x16_bf16(a, bh, accB, 0, 0, 0);
                }
            }
        int oc = lane & 31;
        float s3 = bn3g[oc] * rsqrtf(bn3v[oc] + 1e-5f);
        float sh3 = (c3b[oc] - bn3m[oc]) * s3 + bn3b[oc];
        float pool0 = 0.f, pool1 = 0.f;
        #pragma unroll
        for (int r = 0; r < 16; ++r) {
            float va = fmaxf(fmaf(accA[r], s3, sh3), 0.f);
            float vb = fmaxf(fmaf(accB[r], s3, sh3), 0.f);
            if (((r >> 2) & 1) == 0) { pool0 += va + vb; } else { pool1 += va + vb; }
        }
        int base = n * 512 + oc * 16 + wv * 4 + khalf;
        pooled_bf[base]     = (unsigned short)cvtpk(pool0 * (1.f / 16.f), 0.f);
        pooled_bf[base + 2] = (unsigned short)cvtpk(pool1 * (1.f / 16.f), 0.f);
    }
}

// ---------------------------------------------------------------------------
// Head: FC1 -> FC2 -> L2norm+qsim -> tail MLP, fused. 16 samples/block,
// 512 blocks (R11 configuration — best measured).
// ---------------------------------------------------------------------------
__global__ __launch_bounds__(256) void head_kernel(
    const unsigned short* __restrict__ pooled_bf,
    const unsigned short* __restrict__ fpack1,
    const unsigned short* __restrict__ fpack2,
    const float* __restrict__ f1b, const float* __restrict__ f2b,
    const float* __restrict__ angtab,
    const float* __restrict__ w1, const float* __restrict__ b1,
    const float* __restrict__ cg, const float* __restrict__ cb,
    const float* __restrict__ cm, const float* __restrict__ cv,
    const float* __restrict__ w2, const float* __restrict__ b2,
    const float* __restrict__ w3, const float* __restrict__ b3,
    const float* __restrict__ w4, const float* __restrict__ b4,
    float* __restrict__ out)
{
    __shared__ __align__(16) unsigned short As[8192];   // [16][512]
    __shared__ __align__(16) unsigned short h1[6144];   // [16][384]
    __shared__ __align__(16) unsigned short h2[4096];   // [16][256]

    const int tid = threadIdx.x;
    const int lane = tid & 63;
    const int w = tid >> 6;           // wave 0..3
    const int lr = lane & 15;
    const int lq = lane >> 4;
    const int m0 = blockIdx.x * 16;

    // ---- stage pooled[m0..m0+15][0..511] (coalesced) ----
    {
        const uint4* src = (const uint4*)(pooled_bf + (size_t)m0 * 512);
        #pragma unroll
        for (int i = 0; i < 8; ++i) {
            int q = i * 256 + tid;           // uint4 idx; row=q>>6, kc=q&63
            uint4 v = src[q];
            int row = q >> 6, kc = q & 63;
            int byte = (row * 1024 + 16 * kc) ^ ((row & 7) << 4);
            *(uint4*)((char*)As + byte) = v;
        }
    }
    __syncthreads();   // B1

    // ---- FC1: wave w covers n in [96w, 96w+96), 6 frags; K=512=16 ks ----
    {
        f32x4 acc[6];
        #pragma unroll
        for (int i = 0; i < 6; ++i) acc[i] = (f32x4){0.f, 0.f, 0.f, 0.f};
        for (int ks = 0; ks < 16; ++ks) {
            int byte = (lr * 1024 + 16 * (ks * 4 + lq)) ^ ((lr & 7) << 4);
            bf16x8 act = __builtin_bit_cast(bf16x8, *(const uint4*)((char*)As + byte));
            #pragma unroll
            for (int nf = 0; nf < 6; ++nf) {
                int nb = 6 * w + nf;
                bf16x8 wf = __builtin_bit_cast(bf16x8,
                    *(const uint4*)(fpack1 + (size_t)(nb * 16 + ks) * 512 + lane * 8));
                acc[nf] = __builtin_amdgcn_mfma_f32_16x16x32_bf16(wf, act, acc[nf], 0, 0, 0);
            }
        }
        #pragma unroll
        for (int nf = 0; nf < 6; ++nf) {
            int n0 = 96 * w + 16 * nf + 4 * lq;
            float4 bb = *(const float4*)(f1b + n0);
            unsigned int u0 = cvtpk(relu_(acc[nf][0] + bb.x), relu_(acc[nf][1] + bb.y));
            unsigned int u1 = cvtpk(relu_(acc[nf][2] + bb.z), relu_(acc[nf][3] + bb.w));
            int byte = (lr * 768 + 2 * n0) ^ ((lr & 7) << 4);
            uint2 wr; wr.x = u0; wr.y = u1;
            *(uint2*)((char*)h1 + byte) = wr;
        }
    }
    __syncthreads();   // B2

    // ---- FC2: wave w covers n in [64w, 64w+64), 4 frags; K=384=12 ks ----
    {
        f32x4 acc[4];
        #pragma unroll
        for (int i = 0; i < 4; ++i) acc[i] = (f32x4){0.f, 0.f, 0.f, 0.f};
        for (int ks = 0; ks < 12; ++ks) {
            int byte = (lr * 768 + 16 * (ks * 4 + lq)) ^ ((lr & 7) << 4);
            bf16x8 act = __builtin_bit_cast(bf16x8, *(const uint4*)((char*)h1 + byte));
            #pragma unroll
            for (int nf = 0; nf < 4; ++nf) {
                int nb = 4 * w + nf;
                bf16x8 wf = __builtin_bit_cast(bf16x8,
                    *(const uint4*)(fpack2 + (size_t)(nb * 12 + ks) * 512 + lane * 8));
                acc[nf] = __builtin_amdgcn_mfma_f32_16x16x32_bf16(wf, act, acc[nf], 0, 0, 0);
            }
        }
        #pragma unroll
        for (int nf = 0; nf < 4; ++nf) {
            int n0 = 64 * w + 16 * nf + 4 * lq;
            float4 bb = *(const float4*)(f2b + n0);
            unsigned int u0 = cvtpk(relu_(acc[nf][0] + bb.x), relu_(acc[nf][1] + bb.y));
            unsigned int u1 = cvtpk(relu_(acc[nf][2] + bb.z), relu_(acc[nf][3] + bb.w));
            int byte = (lr * 512 + 2 * n0) ^ ((lr & 7) << 3);
            uint2 wr; wr.x = u0; wr.y = u1;
            *(uint2*)((char*)h2 + byte) = wr;
        }
    }
    __syncthreads();   // B3

    // ---- qsim + tail, 4 samples per wave ----
    const int csrc = lane ^ ((lane >> 1) & 31);
    for (int it = 0; it < 4; ++it) {
        int m = w * 4 + it;
        int byte = (m * 512 + 8 * lane) ^ ((m & 7) << 3);
        uint2 fv = *(const uint2*)((char*)h2 + byte);
        float a0 = bf2f((unsigned short)(fv.x & 0xffff));
        float a1 = bf2f((unsigned short)(fv.x >> 16));
        float a2 = bf2f((unsigned short)(fv.y & 0xffff));
        float a3 = bf2f((unsigned short)(fv.y >> 16));

        float ss = a0 * a0 + a1 * a1 + a2 * a2 + a3 * a3;
        #pragma unroll
        for (int mm = 32; mm; mm >>= 1) ss += __shfl_xor(ss, mm);
        float inv = 1.f / fmaxf(sqrtf(ss), 1e-12f);
        a0 *= inv; a1 *= inv; a2 *= inv; a3 *= inv;

        for (int l = 0; l < 7; ++l) {
            #pragma unroll
            for (int q = 0; q < 6; ++q) {
                float cs = angtab[(l * 8 + q) * 2], sn = angtab[(l * 8 + q) * 2 + 1];
                int mask = 32 >> q;
                float sg = (lane & mask) ? sn : -sn;
                float b0 = __shfl_xor(a0, mask), b1v = __shfl_xor(a1, mask);
                float b2v = __shfl_xor(a2, mask), b3v = __shfl_xor(a3, mask);
                a0 = fmaf(sg, b0, cs * a0); a1 = fmaf(sg, b1v, cs * a1);
                a2 = fmaf(sg, b2v, cs * a2); a3 = fmaf(sg, b3v, cs * a3);
            }
            {
                float cs = angtab[(l * 8 + 6) * 2], sn = angtab[(l * 8 + 6) * 2 + 1];
                float n0 = cs * a0 - sn * a2, n2 = fmaf(sn, a0, cs * a2);
                float n1 = cs * a1 - sn * a3, n3 = fmaf(sn, a1, cs * a3);
                a0 = n0; a1 = n1; a2 = n2; a3 = n3;
            }
            {
                float cs = angtab[(l * 8 + 7) * 2], sn = angtab[(l * 8 + 7) * 2 + 1];
                float n0 = cs * a0 - sn * a1, n1 = fmaf(sn, a0, cs * a1);
                float n2 = cs * a2 - sn * a3, n3 = fmaf(sn, a2, cs * a3);
                a0 = n0; a1 = n1; a2 = n2; a3 = n3;
            }
            a0 = __shfl(a0, csrc); a1 = __shfl(a1, csrc);
            a2 = __shfl(a2, csrc); a3 = __shfl(a3, csrc);
            {
                bool f = (lane & 1);
                float n0 = f ? a2 : a0, n2 = f ? a0 : a2;
                float n1 = f ? a3 : a1, n3 = f ? a1 : a3;
                a0 = n0; a1 = n1; a2 = n2; a3 = n3;
            }
            { float t = a2; a2 = a3; a3 = t; }
        }

        float part = a0 * a0 + a1 * a1 + a2 * a2 + a3 * a3;
        part = (lane & 32) ? -part : part;
        #pragma unroll
        for (int mm = 32; mm; mm >>= 1) part += __shfl_xor(part, mm);
        float qv = part;

        float z = fmaxf(fmaf(qv, w1[lane], b1[lane]), 0.f);
        z = fmaf(z - cm[lane], cg[lane] * rsqrtf(cv[lane] + 1e-5f), cb[lane]);
        {
            int j = lane & 31, hb = lane & 32;
            float acc = 0.f;
            #pragma unroll
            for (int t = 0; t < 32; ++t)
                acc = fmaf(w2[j * 64 + hb + t], __shfl(z, hb + t), acc);
            acc += __shfl_xor(acc, 32);
            z = fmaxf(acc + b2[j], 0.f);
        }
        {
            int j3 = lane & 15, qh = (lane >> 4) & 3;
            float p = 0.f;
            #pragma unroll
            for (int t = 0; t < 8; ++t)
                p = fmaf(w3[j3 * 32 + 8 * qh + t], __shfl(z, 8 * qh + t), p);
            p += __shfl_xor(p, 16);
            p += __shfl_xor(p, 32);
            z = fmaxf(p + b3[j3], 0.f);
        }
        {
            float t4 = w4[lane & 15] * z;
            t4 += __shfl_xor(t4, 1); t4 += __shfl_xor(t4, 2);
            t4 += __shfl_xor(t4, 4); t4 += __shfl_xor(t4, 8);
            float o = t4 + b4[0];
            if (lane == 0) out[m0 + m] = 1.f / (1.f + expf(-o));
        }
    }
}

// ---------------------------------------------------------------------------
extern "C" void kernel_launch(void* const* d_in, const int* in_sizes, int n_in,
                              void* d_out, int out_size, void* d_ws, size_t ws_size,
                              hipStream_t stream)
{
    const float* x    = (const float*)d_in[0];
    const float* c1w  = (const float*)d_in[1];
    const float* c1b  = (const float*)d_in[2];
    const float* bn1g = (const float*)d_in[3];
    const float* bn1b = (const float*)d_in[4];
    const float* bn1m = (const float*)d_in[5];
    const float* bn1v = (const float*)d_in[6];
    const float* c2w  = (const float*)d_in[7];
    const float* c2b  = (const float*)d_in[8];
    const float* bn2g = (const float*)d_in[9];
    const float* bn2b = (const float*)d_in[10];
    const float* bn2m = (const float*)d_in[11];
    const float* bn2v = (const float*)d_in[12];
    const float* c3w  = (const float*)d_in[13];
    const float* c3b  = (const float*)d_in[14];
    const float* bn3g = (const float*)d_in[15];
    const float* bn3b = (const float*)d_in[16];
    const float* bn3m = (const float*)d_in[17];
    const float* bn3v = (const float*)d_in[18];
    const float* f1w  = (const float*)d_in[19];
    const float* f1b  = (const float*)d_in[20];
    const float* f2w  = (const float*)d_in[21];
    const float* f2b  = (const float*)d_in[22];
    const float* qw   = (const float*)d_in[23];
    const float* w1   = (const float*)d_in[24];
    const float* b1   = (const float*)d_in[25];
    const float* cg   = (const float*)d_in[26];
    const float* cb   = (const float*)d_in[27];
    const float* cm   = (const float*)d_in[28];
    const float* cv   = (const float*)d_in[29];
    const float* w2   = (const float*)d_in[30];
    const float* b2   = (const float*)d_in[31];
    const float* w3   = (const float*)d_in[32];
    const float* b3   = (const float*)d_in[33];
    const float* w4   = (const float*)d_in[34];
    const float* b4   = (const float*)d_in[35];

    unsigned short* ws = (unsigned short*)d_ws;
    unsigned short* pooled_bf = ws;                              // 8192*512 ush
    unsigned short* cpack     = pooled_bf + (size_t)BATCH * 512;
    unsigned short* fpack1    = cpack + CPACK_TOTAL;
    unsigned short* fpack2    = fpack1 + FC1_TOTAL;
    float*          angtab    = (float*)(fpack2 + FC2_TOTAL);

    prepack_kernel<<<(PREP_TOTAL + 255) / 256, 256, 0, stream>>>(
        c1w, c2w, c3w, f1w, f2w, qw, cpack, fpack1, fpack2, angtab);

    fused_cnn_mfma<<<BATCH, 256, 0, stream>>>(
        x, c1b, bn1g, bn1b, bn1m, bn1v,
        c2b, bn2g, bn2b, bn2m, bn2v,
        c3b, bn3g, bn3b, bn3m, bn3v, cpack, pooled_bf);

    head_kernel<<<BATCH / 16, 256, 0, stream>>>(
        pooled_bf, fpack1, fpack2, f1b, f2b, angtab,
        w1, b1, cg, cb, cm, cv, w2, b2, w3, b3, w4, b4, (float*)d_out);
}

// Round 14
// 111.768 us; speedup vs baseline: 1.0444x; 1.0085x over previous
//
#include <hip/hip_runtime.h>
#include <hip/hip_bf16.h>
#include <math.h>

#define BATCH 8192

typedef __attribute__((ext_vector_type(8))) short bf16x8;
typedef __attribute__((ext_vector_type(4))) float f32x4;
typedef __attribute__((ext_vector_type(16))) float f32x16;

// 8B value with only 4B alignment guarantee -> ds_read2/ds_write2
struct u2a4 { unsigned int x, y; };

__device__ __forceinline__ unsigned short f2bf(float f) {
    unsigned int u = __builtin_bit_cast(unsigned int, f);
    u = (u + 0x7FFFu + ((u >> 16) & 1u)) >> 16;
    return (unsigned short)u;
}
__device__ __forceinline__ float bf2f(unsigned short h) {
    unsigned int u = ((unsigned int)h) << 16;
    return __builtin_bit_cast(float, u);
}
__device__ __forceinline__ unsigned int cvtpk(float a, float b) {
    unsigned int r;
    asm("v_cvt_pk_bf16_f32 %0, %1, %2" : "=v"(r) : "v"(a), "v"(b));
    return r;
}
__device__ __forceinline__ int swz(int i) { return i ^ ((i >> 3) & 3); }
__device__ __forceinline__ float relu_(float v) { return fmaxf(v, 0.f); }

// ---- weight fragment pack (ushorts) ----
#define W1OFF 0
#define W1FRAGS 4
#define W2OFF (W1OFF + W1FRAGS * 512)
#define W2FRAGS 6
#define W3OFF (W2OFF + W2FRAGS * 512)
#define W3FRAGS 18
#define CPACK_TOTAL (W3OFF + W3FRAGS * 512)
#define FC1_FRAGS (24 * 16)          // nb x ks, hi only
#define FC2_FRAGS (16 * 12)
#define FC1_TOTAL (FC1_FRAGS * 512)  // 196608
#define FC2_TOTAL (FC2_FRAGS * 512)  // 98304
#define ANG_TOTAL 112
#define PREP_TOTAL (CPACK_TOTAL + FC1_TOTAL + FC2_TOTAL + ANG_TOTAL)

// ---------------------------------------------------------------------------
__global__ __launch_bounds__(256) void prepack_kernel(
    const float* __restrict__ c1w, const float* __restrict__ c2w,
    const float* __restrict__ c3w, const float* __restrict__ f1w,
    const float* __restrict__ f2w, const float* __restrict__ qw,
    unsigned short* __restrict__ cpack, unsigned short* __restrict__ fpack1,
    unsigned short* __restrict__ fpack2, float* __restrict__ angtab)
{
    int e = blockIdx.x * 256 + threadIdx.x;
    if (e >= PREP_TOTAL) return;

    if (e < CPACK_TOTAL) {
        int f = e >> 9, r = e & 511;
        int l = r >> 3, j = r & 7;
        float w = 0.f; int hl = 0;
        if (f < W1FRAGS) {
            int sel = f >> 1; hl = f & 1;
            int oc = l & 15;
            int k = 8 * (l >> 4) + j;
            int ky, kx;
            if (sel == 0) { ky = k >> 3; kx = k & 7; }
            else          { ky = 4;      kx = k; }
            if (kx < 5 && ky < 5 && oc < 8) w = c1w[oc * 25 + ky * 5 + kx];
        } else if (f < W1FRAGS + W2FRAGS) {
            int f2 = f - W1FRAGS;
            int ky = f2 >> 1; hl = f2 & 1;
            int k = 8 * (l >> 4) + j;
            int kx = k >> 3, ic = k & 7, oc = l & 15;
            if (kx < 3) w = c2w[((oc * 8 + ic) * 3 + ky) * 3 + kx];
        } else {
            int f3 = f - W1FRAGS - W2FRAGS;      // (ky*3+kx)*2+hl
            int ky = f3 / 6, kx = (f3 / 2) % 3; hl = f3 & 1;
            int oc = l & 31, ic = 8 * (l >> 5) + j;
            w = c3w[((oc * 16 + ic) * 3 + ky) * 3 + kx];
        }
        unsigned short hv = f2bf(w);
        unsigned short lv = f2bf(w - bf2f(hv));
        cpack[e] = hl ? lv : hv;
        return;
    }
    e -= CPACK_TOTAL;
    if (e < FC1_TOTAL) {
        int phi = e >> 9, r = e & 511;
        int l = r >> 3, j = r & 7;
        int ks = phi & 15, nb = phi >> 4;
        int n = nb * 16 + (l & 15);
        int kg = ks * 32 + 8 * (l >> 4) + j;
        fpack1[e] = f2bf(f1w[n * 512 + kg]);
        return;
    }
    e -= FC1_TOTAL;
    if (e < FC2_TOTAL) {
        int phi = e >> 9, r = e & 511;
        int l = r >> 3, j = r & 7;
        int ks = phi % 12, nb = phi / 12;
        int n = nb * 16 + (l & 15);
        int kg = ks * 32 + 8 * (l >> 4) + j;
        fpack2[e] = f2bf(f2w[n * 384 + kg]);
        return;
    }
    e -= FC2_TOTAL;
    {
        int a = e >> 1;
        float th = 0.5f * qw[a];
        angtab[e] = (e & 1) ? sinf(th) : cosf(th);
    }
}

// ---------------------------------------------------------------------------
// Fused CNN. xp layout: 40 dw/row = [4 pad][32 interior][4 pad]; pixel j at
// dword (j>>1)+4 -> 16B-aligned staging writes (ds_write_b128, conflict-free).
// conv1 reads at +3. Everything else R8/R10 structure.
// ---------------------------------------------------------------------------
__global__ __launch_bounds__(256) void fused_cnn_mfma(
    const float* __restrict__ x,
    const float* __restrict__ c1b,
    const float* __restrict__ bn1g, const float* __restrict__ bn1b,
    const float* __restrict__ bn1m, const float* __restrict__ bn1v,
    const float* __restrict__ c2b,
    const float* __restrict__ bn2g, const float* __restrict__ bn2b,
    const float* __restrict__ bn2m, const float* __restrict__ bn2v,
    const float* __restrict__ c3b,
    const float* __restrict__ bn3g, const float* __restrict__ bn3b,
    const float* __restrict__ bn3m, const float* __restrict__ bn3v,
    const unsigned short* __restrict__ cpack,
    unsigned short* __restrict__ pooled_bf)
{
    __shared__ __align__(16) uint4 h1p4[1160];
    __shared__ __align__(16) unsigned int sd[2720];

    uint4* sbuf4 = (uint4*)sd;

    const int tid = threadIdx.x;
    const int lane = tid & 63;
    const int wv = tid >> 6;
    const int n = blockIdx.x;
    const int lrow = lane & 15;
    const int lq = lane >> 4;

    // ---- P0: stage x (8 px/thread -> one aligned b128 write) + zero pads ----
    {
        const float4* xv = (const float4*)(x + (size_t)n * 4096);
        #pragma unroll
        for (int i = 0; i < 2; ++i) {
            int u = tid + 256 * i;              // 512 units: row y = u>>3, 8-px col c8
            int y = u >> 3, c8 = u & 7;
            float4 va = xv[y * 16 + c8 * 2];
            float4 vb = xv[y * 16 + c8 * 2 + 1];
            uint4 st;
            st.x = cvtpk(va.x, va.y); st.y = cvtpk(va.z, va.w);
            st.z = cvtpk(vb.x, vb.y); st.w = cvtpk(vb.z, vb.w);
            *(uint4*)&sd[(y + 2) * 40 + 4 + c8 * 4] = st;     // 16B aligned
        }
        // pads: rows 0,1 and 66,67 -> dwords 3..36; rows 2..65 -> dwords 3, 36
        if (tid < 68)       { int r = tid / 34, c = tid % 34; sd[r * 40 + c + 3] = 0u; }
        else if (tid < 136) { int u = tid - 68; int r = 66 + u / 34, c = u % 34; sd[r * 40 + c + 3] = 0u; }
        if (tid < 128) { int r = 2 + (tid & 63); sd[r * 40 + ((tid >> 6) ? 36 : 3)] = 0u; }
        if (tid < 132) {
            int p;
            if (tid < 34) p = tid;
            else if (tid < 68) p = 33 * 34 + (tid - 34);
            else { int r = 1 + ((tid - 68) & 31); int side = (tid - 68) >> 5; p = r * 34 + side * 33; }
            h1p4[swz(p)] = (uint4){0u, 0u, 0u, 0u};
        }
    }
    __syncthreads();   // B1

    // ---- conv1 (swapped, hi only) ----
    {
        bf16x8 wf0 = __builtin_bit_cast(bf16x8, *(const uint4*)(cpack + W1OFF + lane * 8));
        bf16x8 wf2 = __builtin_bit_cast(bf16x8, *(const uint4*)(cpack + W1OFF + 2 * 512 + lane * 8));
        float s1v[4], sh1v[4];
        #pragma unroll
        for (int r = 0; r < 4; ++r) {
            int oc = (4 * lq + r) & 7;
            s1v[r] = bn1g[oc] * rsqrtf(bn1v[oc] + 1e-5f);
            sh1v[r] = (c1b[oc] - bn1m[oc]) * s1v[r] + bn1b[oc];
        }
        #pragma unroll 4
        for (int t = 0; t < 16; ++t) {
            int oy = wv * 8 + (t >> 1), h = t & 1;
            int a1 = (2 * oy + lq) * 40 + 16 * h + lrow + 3;
            u2a4 r1 = *(const u2a4*)&sd[a1];
            uint4 d1; d1.x = r1.x; d1.y = r1.y; d1.z = sd[a1 + 2]; d1.w = 0u;
            int a2 = (2 * oy + 4) * 40 + 16 * h + lrow + 3;
            u2a4 r2 = *(const u2a4*)&sd[a2];
            uint4 d2; d2.x = r2.x; d2.y = r2.y; d2.z = sd[a2 + 2]; d2.w = 0u;
            f32x4 acc = {0.f, 0.f, 0.f, 0.f};
            acc = __builtin_amdgcn_mfma_f32_16x16x32_bf16(wf0, __builtin_bit_cast(bf16x8, d1), acc, 0, 0, 0);
            acc = __builtin_amdgcn_mfma_f32_16x16x32_bf16(wf2, __builtin_bit_cast(bf16x8, d2), acc, 0, 0, 0);
            if (lq < 2) {
                unsigned int u0 = cvtpk(fmaxf(fmaf(acc[0], s1v[0], sh1v[0]), 0.f),
                                        fmaxf(fmaf(acc[1], s1v[1], sh1v[1]), 0.f));
                unsigned int u1 = cvtpk(fmaxf(fmaf(acc[2], s1v[2], sh1v[2]), 0.f),
                                        fmaxf(fmaf(acc[3], s1v[3], sh1v[3]), 0.f));
                int p = (oy + 1) * 34 + 16 * h + lrow + 1;
                uint2 wr; wr.x = u0; wr.y = u1;
                *(uint2*)((char*)h1p4 + swz(p) * 16 + 8 * lq) = wr;
            }
        }
    }
    __syncthreads();   // B2

    // ---- P2: zero h2p ring (planar) + conv2 (swapped, hi only) ----
    {
        if (tid < 136) {
            int pp = tid >> 1, plane = tid & 1;
            int p;
            if (pp < 18) p = pp;
            else if (pp < 36) p = 17 * 18 + (pp - 18);
            else { int r = 1 + ((pp - 36) & 15); int side = (pp - 36) >> 4; p = r * 18 + side * 17; }
            sbuf4[plane * 324 + p] = (uint4){0u, 0u, 0u, 0u};
        }
        bf16x8 w2f[3];
        #pragma unroll
        for (int ky = 0; ky < 3; ++ky)
            w2f[ky] = __builtin_bit_cast(bf16x8,
                *(const uint4*)(cpack + W2OFF + (ky * 2) * 512 + lane * 8));
        float s2v[4], sh2v[4];
        #pragma unroll
        for (int r = 0; r < 4; ++r) {
            int oc = 4 * lq + r;
            s2v[r] = bn2g[oc] * rsqrtf(bn2v[oc] + 1e-5f);
            sh2v[r] = (c2b[oc] - bn2m[oc]) * s2v[r] + bn2b[oc];
        }
        int lqe = (lq == 3) ? 0 : lq;
        #pragma unroll
        for (int t = 0; t < 4; ++t) {
            int oy = 4 * wv + t;
            f32x4 acc = {0.f, 0.f, 0.f, 0.f};
            #pragma unroll
            for (int ky = 0; ky < 3; ++ky) {
                int iy = 2 * oy + ky;
                int p = iy * 34 + 2 * lrow + lqe;
                bf16x8 b = __builtin_bit_cast(bf16x8, h1p4[swz(p)]);
                acc = __builtin_amdgcn_mfma_f32_16x16x32_bf16(w2f[ky], b, acc, 0, 0, 0);
            }
            unsigned int u0 = cvtpk(fmaxf(fmaf(acc[0], s2v[0], sh2v[0]), 0.f),
                                    fmaxf(fmaf(acc[1], s2v[1], sh2v[1]), 0.f));
            unsigned int u1 = cvtpk(fmaxf(fmaf(acc[2], s2v[2], sh2v[2]), 0.f),
                                    fmaxf(fmaf(acc[3], s2v[3], sh2v[3]), 0.f));
            int p = (oy + 1) * 18 + lrow + 1;
            uint2 wr; wr.x = u0; wr.y = u1;
            *(uint2*)((char*)sbuf4 + ((lq >> 1) * 324 + p) * 16 + 8 * (lq & 1)) = wr;
        }
    }
    __syncthreads();   // B3

    // ---- conv3 (32x32x16, hi only) + BN/ReLU + pool ----
    {
        f32x16 accA = {0.f}, accB = {0.f};
        const int row = lane & 31;
        const int khalf = lane >> 5;
        const int kbase = khalf * 324;
        #pragma unroll
        for (int ky = 0; ky < 3; ++ky)
            #pragma unroll
            for (int kx = 0; kx < 3; ++kx) {
                int fb = (ky * 3 + kx) * 2;
                bf16x8 bh = __builtin_bit_cast(bf16x8, *(const uint4*)(cpack + W3OFF + fb * 512 + lane * 8));
                {
                    int pix = (4 * wv + 0 + (row >> 4) + ky) * 18 + (row & 15) + kx;
                    bf16x8 a = __builtin_bit_cast(bf16x8, sbuf4[kbase + pix]);
                    accA = __builtin_amdgcn_mfma_f32_32x32x16_bf16(a, bh, accA, 0, 0, 0);
                }
                {
                    int pix = (4 * wv + 2 + (row >> 4) + ky) * 18 + (row & 15) + kx;
                    bf16x8 a = __builtin_bit_cast(bf16x8, sbuf4[kbase + pix]);
                    accB = __builtin_amdgcn_mfma_f32_32x32x16_bf16(a, bh, accB, 0, 0, 0);
                }
            }
        int oc = lane & 31;
        float s3 = bn3g[oc] * rsqrtf(bn3v[oc] + 1e-5f);
        float sh3 = (c3b[oc] - bn3m[oc]) * s3 + bn3b[oc];
        float pool0 = 0.f, pool1 = 0.f;
        #pragma unroll
        for (int r = 0; r < 16; ++r) {
            float va = fmaxf(fmaf(accA[r], s3, sh3), 0.f);
            float vb = fmaxf(fmaf(accB[r], s3, sh3), 0.f);
            if (((r >> 2) & 1) == 0) { pool0 += va + vb; } else { pool1 += va + vb; }
        }
        int base = n * 512 + oc * 16 + wv * 4 + khalf;
        pooled_bf[base]     = (unsigned short)cvtpk(pool0 * (1.f / 16.f), 0.f);
        pooled_bf[base + 2] = (unsigned short)cvtpk(pool1 * (1.f / 16.f), 0.f);
    }
}

// ---------------------------------------------------------------------------
// Head: FC1 -> FC2 -> L2norm+qsim -> tail MLP (R11 configuration).
// ---------------------------------------------------------------------------
__global__ __launch_bounds__(256) void head_kernel(
    const unsigned short* __restrict__ pooled_bf,
    const unsigned short* __restrict__ fpack1,
    const unsigned short* __restrict__ fpack2,
    const float* __restrict__ f1b, const float* __restrict__ f2b,
    const float* __restrict__ angtab,
    const float* __restrict__ w1, const float* __restrict__ b1,
    const float* __restrict__ cg, const float* __restrict__ cb,
    const float* __restrict__ cm, const float* __restrict__ cv,
    const float* __restrict__ w2, const float* __restrict__ b2,
    const float* __restrict__ w3, const float* __restrict__ b3,
    const float* __restrict__ w4, const float* __restrict__ b4,
    float* __restrict__ out)
{
    __shared__ __align__(16) unsigned short As[8192];   // [16][512]
    __shared__ __align__(16) unsigned short h1[6144];   // [16][384]
    __shared__ __align__(16) unsigned short h2[4096];   // [16][256]

    const int tid = threadIdx.x;
    const int lane = tid & 63;
    const int w = tid >> 6;
    const int lr = lane & 15;
    const int lq = lane >> 4;
    const int m0 = blockIdx.x * 16;

    {
        const uint4* src = (const uint4*)(pooled_bf + (size_t)m0 * 512);
        #pragma unroll
        for (int i = 0; i < 8; ++i) {
            int q = i * 256 + tid;
            uint4 v = src[q];
            int row = q >> 6, kc = q & 63;
            int byte = (row * 1024 + 16 * kc) ^ ((row & 7) << 4);
            *(uint4*)((char*)As + byte) = v;
        }
    }
    __syncthreads();   // B1

    {
        f32x4 acc[6];
        #pragma unroll
        for (int i = 0; i < 6; ++i) acc[i] = (f32x4){0.f, 0.f, 0.f, 0.f};
        for (int ks = 0; ks < 16; ++ks) {
            int byte = (lr * 1024 + 16 * (ks * 4 + lq)) ^ ((lr & 7) << 4);
            bf16x8 act = __builtin_bit_cast(bf16x8, *(const uint4*)((char*)As + byte));
            #pragma unroll
            for (int nf = 0; nf < 6; ++nf) {
                int nb = 6 * w + nf;
                bf16x8 wf = __builtin_bit_cast(bf16x8,
                    *(const uint4*)(fpack1 + (size_t)(nb * 16 + ks) * 512 + lane * 8));
                acc[nf] = __builtin_amdgcn_mfma_f32_16x16x32_bf16(wf, act, acc[nf], 0, 0, 0);
            }
        }
        #pragma unroll
        for (int nf = 0; nf < 6; ++nf) {
            int n0 = 96 * w + 16 * nf + 4 * lq;
            float4 bb = *(const float4*)(f1b + n0);
            unsigned int u0 = cvtpk(relu_(acc[nf][0] + bb.x), relu_(acc[nf][1] + bb.y));
            unsigned int u1 = cvtpk(relu_(acc[nf][2] + bb.z), relu_(acc[nf][3] + bb.w));
            int byte = (lr * 768 + 2 * n0) ^ ((lr & 7) << 4);
            uint2 wr; wr.x = u0; wr.y = u1;
            *(uint2*)((char*)h1 + byte) = wr;
        }
    }
    __syncthreads();   // B2

    {
        f32x4 acc[4];
        #pragma unroll
        for (int i = 0; i < 4; ++i) acc[i] = (f32x4){0.f, 0.f, 0.f, 0.f};
        for (int ks = 0; ks < 12; ++ks) {
            int byte = (lr * 768 + 16 * (ks * 4 + lq)) ^ ((lr & 7) << 4);
            bf16x8 act = __builtin_bit_cast(bf16x8, *(const uint4*)((char*)h1 + byte));
            #pragma unroll
            for (int nf = 0; nf < 4; ++nf) {
                int nb = 4 * w + nf;
                bf16x8 wf = __builtin_bit_cast(bf16x8,
                    *(const uint4*)(fpack2 + (size_t)(nb * 12 + ks) * 512 + lane * 8));
                acc[nf] = __builtin_amdgcn_mfma_f32_16x16x32_bf16(wf, act, acc[nf], 0, 0, 0);
            }
        }
        #pragma unroll
        for (int nf = 0; nf < 4; ++nf) {
            int n0 = 64 * w + 16 * nf + 4 * lq;
            float4 bb = *(const float4*)(f2b + n0);
            unsigned int u0 = cvtpk(relu_(acc[nf][0] + bb.x), relu_(acc[nf][1] + bb.y));
            unsigned int u1 = cvtpk(relu_(acc[nf][2] + bb.z), relu_(acc[nf][3] + bb.w));
            int byte = (lr * 512 + 2 * n0) ^ ((lr & 7) << 3);
            uint2 wr; wr.x = u0; wr.y = u1;
            *(uint2*)((char*)h2 + byte) = wr;
        }
    }
    __syncthreads();   // B3

    const int csrc = lane ^ ((lane >> 1) & 31);
    for (int it = 0; it < 4; ++it) {
        int m = w * 4 + it;
        int byte = (m * 512 + 8 * lane) ^ ((m & 7) << 3);
        uint2 fv = *(const uint2*)((char*)h2 + byte);
        float a0 = bf2f((unsigned short)(fv.x & 0xffff));
        float a1 = bf2f((unsigned short)(fv.x >> 16));
        float a2 = bf2f((unsigned short)(fv.y & 0xffff));
        float a3 = bf2f((unsigned short)(fv.y >> 16));

        float ss = a0 * a0 + a1 * a1 + a2 * a2 + a3 * a3;
        #pragma unroll
        for (int mm = 32; mm; mm >>= 1) ss += __shfl_xor(ss, mm);
        float inv = 1.f / fmaxf(sqrtf(ss), 1e-12f);
        a0 *= inv; a1 *= inv; a2 *= inv; a3 *= inv;

        for (int l = 0; l < 7; ++l) {
            #pragma unroll
            for (int q = 0; q < 6; ++q) {
                float cs = angtab[(l * 8 + q) * 2], sn = angtab[(l * 8 + q) * 2 + 1];
                int mask = 32 >> q;
                float sg = (lane & mask) ? sn : -sn;
                float b0 = __shfl_xor(a0, mask), b1v = __shfl_xor(a1, mask);
                float b2v = __shfl_xor(a2, mask), b3v = __shfl_xor(a3, mask);
                a0 = fmaf(sg, b0, cs * a0); a1 = fmaf(sg, b1v, cs * a1);
                a2 = fmaf(sg, b2v, cs * a2); a3 = fmaf(sg, b3v, cs * a3);
            }
            {
                float cs = angtab[(l * 8 + 6) * 2], sn = angtab[(l * 8 + 6) * 2 + 1];
                float n0 = cs * a0 - sn * a2, n2 = fmaf(sn, a0, cs * a2);
                float n1 = cs * a1 - sn * a3, n3 = fmaf(sn, a1, cs * a3);
                a0 = n0; a1 = n1; a2 = n2; a3 = n3;
            }
            {
                float cs = angtab[(l * 8 + 7) * 2], sn = angtab[(l * 8 + 7) * 2 + 1];
                float n0 = cs * a0 - sn * a1, n1 = fmaf(sn, a0, cs * a1);
                float n2 = cs * a2 - sn * a3, n3 = fmaf(sn, a2, cs * a3);
                a0 = n0; a1 = n1; a2 = n2; a3 = n3;
            }
            a0 = __shfl(a0, csrc); a1 = __shfl(a1, csrc);
            a2 = __shfl(a2, csrc); a3 = __shfl(a3, csrc);
            {
                bool f = (lane & 1);
                float n0 = f ? a2 : a0, n2 = f ? a0 : a2;
                float n1 = f ? a3 : a1, n3 = f ? a1 : a3;
                a0 = n0; a1 = n1; a2 = n2; a3 = n3;
            }
            { float t = a2; a2 = a3; a3 = t; }
        }

        float part = a0 * a0 + a1 * a1 + a2 * a2 + a3 * a3;
        part = (lane & 32) ? -part : part;
        #pragma unroll
        for (int mm = 32; mm; mm >>= 1) part += __shfl_xor(part, mm);
        float qv = part;

        float z = fmaxf(fmaf(qv, w1[lane], b1[lane]), 0.f);
        z = fmaf(z - cm[lane], cg[lane] * rsqrtf(cv[lane] + 1e-5f), cb[lane]);
        {
            int j = lane & 31, hb = lane & 32;
            float acc = 0.f;
            #pragma unroll
            for (int t = 0; t < 32; ++t)
                acc = fmaf(w2[j * 64 + hb + t], __shfl(z, hb + t), acc);
            acc += __shfl_xor(acc, 32);
            z = fmaxf(acc + b2[j], 0.f);
        }
        {
            int j3 = lane & 15, qh = (lane >> 4) & 3;
            float p = 0.f;
            #pragma unroll
            for (int t = 0; t < 8; ++t)
                p = fmaf(w3[j3 * 32 + 8 * qh + t], __shfl(z, 8 * qh + t), p);
            p += __shfl_xor(p, 16);
            p += __shfl_xor(p, 32);
            z = fmaxf(p + b3[j3], 0.f);
        }
        {
            float t4 = w4[lane & 15] * z;
            t4 += __shfl_xor(t4, 1); t4 += __shfl_xor(t4, 2);
            t4 += __shfl_xor(t4, 4); t4 += __shfl_xor(t4, 8);
            float o = t4 + b4[0];
            if (lane == 0) out[m0 + m] = 1.f / (1.f + expf(-o));
        }
    }
}

// ---------------------------------------------------------------------------
extern "C" void kernel_launch(void* const* d_in, const int* in_sizes, int n_in,
                              void* d_out, int out_size, void* d_ws, size_t ws_size,
                              hipStream_t stream)
{
    const float* x    = (const float*)d_in[0];
    const float* c1w  = (const float*)d_in[1];
    const float* c1b  = (const float*)d_in[2];
    const float* bn1g = (const float*)d_in[3];
    const float* bn1b = (const float*)d_in[4];
    const float* bn1m = (const float*)d_in[5];
    const float* bn1v = (const float*)d_in[6];
    const float* c2w  = (const float*)d_in[7];
    const float* c2b  = (const float*)d_in[8];
    const float* bn2g = (const float*)d_in[9];
    const float* bn2b = (const float*)d_in[10];
    const float* bn2m = (const float*)d_in[11];
    const float* bn2v = (const float*)d_in[12];
    const float* c3w  = (const float*)d_in[13];
    const float* c3b  = (const float*)d_in[14];
    const float* bn3g = (const float*)d_in[15];
    const float* bn3b = (const float*)d_in[16];
    const float* bn3m = (const float*)d_in[17];
    const float* bn3v = (const float*)d_in[18];
    const float* f1w  = (const float*)d_in[19];
    const float* f1b  = (const float*)d_in[20];
    const float* f2w  = (const float*)d_in[21];
    const float* f2b  = (const float*)d_in[22];
    const float* qw   = (const float*)d_in[23];
    const float* w1   = (const float*)d_in[24];
    const float* b1   = (const float*)d_in[25];
    const float* cg   = (const float*)d_in[26];
    const float* cb   = (const float*)d_in[27];
    const float* cm   = (const float*)d_in[28];
    const float* cv   = (const float*)d_in[29];
    const float* w2   = (const float*)d_in[30];
    const float* b2   = (const float*)d_in[31];
    const float* w3   = (const float*)d_in[32];
    const float* b3   = (const float*)d_in[33];
    const float* w4   = (const float*)d_in[34];
    const float* b4   = (const float*)d_in[35];

    unsigned short* ws = (unsigned short*)d_ws;
    unsigned short* pooled_bf = ws;                              // 8192*512 ush
    unsigned short* cpack     = pooled_bf + (size_t)BATCH * 512;
    unsigned short* fpack1    = cpack + CPACK_TOTAL;
    unsigned short* fpack2    = fpack1 + FC1_TOTAL;
    float*          angtab    = (float*)(fpack2 + FC2_TOTAL);

    prepack_kernel<<<(PREP_TOTAL + 255) / 256, 256, 0, stream>>>(
        c1w, c2w, c3w, f1w, f2w, qw, cpack, fpack1, fpack2, angtab);

    fused_cnn_mfma<<<BATCH, 256, 0, stream>>>(
        x, c1b, bn1g, bn1b, bn1m, bn1v,
        c2b, bn2g, bn2b, bn2m, bn2v,
        c3b, bn3g, bn3b, bn3m, bn3v, cpack, pooled_bf);

    head_kernel<<<BATCH / 16, 256, 0, stream>>>(
        pooled_bf, fpack1, fpack2, f1b, f2b, angtab,
        w1, b1, cg, cb, cm, cv, w2, b2, w3, b3, w4, b4, (float*)d_out);
}

// Round 15
// 103.995 us; speedup vs baseline: 1.1225x; 1.0747x over previous
//
#include <hip/hip_runtime.h>
#include <hip/hip_bf16.h>
#include <math.h>

#define BATCH 8192

typedef __attribute__((ext_vector_type(8))) short bf16x8;
typedef __attribute__((ext_vector_type(4))) float f32x4;
typedef __attribute__((ext_vector_type(16))) float f32x16;

// 8B value with only 4B alignment guarantee -> ds_read2/ds_write2
struct u2a4 { unsigned int x, y; };

__device__ __forceinline__ unsigned short f2bf(float f) {
    unsigned int u = __builtin_bit_cast(unsigned int, f);
    u = (u + 0x7FFFu + ((u >> 16) & 1u)) >> 16;
    return (unsigned short)u;
}
__device__ __forceinline__ float bf2f(unsigned short h) {
    unsigned int u = ((unsigned int)h) << 16;
    return __builtin_bit_cast(float, u);
}
__device__ __forceinline__ unsigned int cvtpk(float a, float b) {
    unsigned int r;
    asm("v_cvt_pk_bf16_f32 %0, %1, %2" : "=v"(r) : "v"(a), "v"(b));
    return r;
}
__device__ __forceinline__ int swz(int i) { return i ^ ((i >> 3) & 3); }
__device__ __forceinline__ float relu_(float v) { return fmaxf(v, 0.f); }

// ---- weight fragment pack (ushorts) ----
#define W1OFF 0
#define W1FRAGS 4
#define W2OFF (W1OFF + W1FRAGS * 512)
#define W2FRAGS 6
#define W3OFF (W2OFF + W2FRAGS * 512)
#define W3FRAGS 18
#define CPACK_TOTAL (W3OFF + W3FRAGS * 512)
#define FC1_FRAGS (24 * 16)          // nb x ks, hi only
#define FC2_FRAGS (16 * 12)
#define FC1_TOTAL (FC1_FRAGS * 512)  // 196608
#define FC2_TOTAL (FC2_FRAGS * 512)  // 98304
#define ANG_TOTAL 112
#define PREP_TOTAL (CPACK_TOTAL + FC1_TOTAL + FC2_TOTAL + ANG_TOTAL)

// ---------------------------------------------------------------------------
__global__ __launch_bounds__(256) void prepack_kernel(
    const float* __restrict__ c1w, const float* __restrict__ c2w,
    const float* __restrict__ c3w, const float* __restrict__ f1w,
    const float* __restrict__ f2w, const float* __restrict__ qw,
    unsigned short* __restrict__ cpack, unsigned short* __restrict__ fpack1,
    unsigned short* __restrict__ fpack2, float* __restrict__ angtab)
{
    int e = blockIdx.x * 256 + threadIdx.x;
    if (e >= PREP_TOTAL) return;

    if (e < CPACK_TOTAL) {
        int f = e >> 9, r = e & 511;
        int l = r >> 3, j = r & 7;
        float w = 0.f; int hl = 0;
        if (f < W1FRAGS) {
            int sel = f >> 1; hl = f & 1;
            int oc = l & 15;
            int k = 8 * (l >> 4) + j;
            int ky, kx;
            if (sel == 0) { ky = k >> 3; kx = k & 7; }
            else          { ky = 4;      kx = k; }
            if (kx < 5 && ky < 5 && oc < 8) w = c1w[oc * 25 + ky * 5 + kx];
        } else if (f < W1FRAGS + W2FRAGS) {
            int f2 = f - W1FRAGS;
            int ky = f2 >> 1; hl = f2 & 1;
            int k = 8 * (l >> 4) + j;
            int kx = k >> 3, ic = k & 7, oc = l & 15;
            if (kx < 3) w = c2w[((oc * 8 + ic) * 3 + ky) * 3 + kx];
        } else {
            int f3 = f - W1FRAGS - W2FRAGS;      // (ky*3+kx)*2+hl
            int ky = f3 / 6, kx = (f3 / 2) % 3; hl = f3 & 1;
            int oc = l & 31, ic = 8 * (l >> 5) + j;
            w = c3w[((oc * 16 + ic) * 3 + ky) * 3 + kx];
        }
        unsigned short hv = f2bf(w);
        unsigned short lv = f2bf(w - bf2f(hv));
        cpack[e] = hl ? lv : hv;
        return;
    }
    e -= CPACK_TOTAL;
    if (e < FC1_TOTAL) {
        int phi = e >> 9, r = e & 511;
        int l = r >> 3, j = r & 7;
        int ks = phi & 15, nb = phi >> 4;
        int n = nb * 16 + (l & 15);
        int kg = ks * 32 + 8 * (l >> 4) + j;
        fpack1[e] = f2bf(f1w[n * 512 + kg]);
        return;
    }
    e -= FC1_TOTAL;
    if (e < FC2_TOTAL) {
        int phi = e >> 9, r = e & 511;
        int l = r >> 3, j = r & 7;
        int ks = phi % 12, nb = phi / 12;
        int n = nb * 16 + (l & 15);
        int kg = ks * 32 + 8 * (l >> 4) + j;
        fpack2[e] = f2bf(f2w[n * 384 + kg]);
        return;
    }
    e -= FC2_TOTAL;
    {
        int a = e >> 1;
        float th = 0.5f * qw[a];
        angtab[e] = (e & 1) ? sinf(th) : cosf(th);
    }
}

// ---------------------------------------------------------------------------
// Fused CNN (R14 structure — best measured: ~80 us).
// ---------------------------------------------------------------------------
__global__ __launch_bounds__(256) void fused_cnn_mfma(
    const float* __restrict__ x,
    const float* __restrict__ c1b,
    const float* __restrict__ bn1g, const float* __restrict__ bn1b,
    const float* __restrict__ bn1m, const float* __restrict__ bn1v,
    const float* __restrict__ c2b,
    const float* __restrict__ bn2g, const float* __restrict__ bn2b,
    const float* __restrict__ bn2m, const float* __restrict__ bn2v,
    const float* __restrict__ c3b,
    const float* __restrict__ bn3g, const float* __restrict__ bn3b,
    const float* __restrict__ bn3m, const float* __restrict__ bn3v,
    const unsigned short* __restrict__ cpack,
    unsigned short* __restrict__ pooled_bf)
{
    __shared__ __align__(16) uint4 h1p4[1160];
    __shared__ __align__(16) unsigned int sd[2720];

    uint4* sbuf4 = (uint4*)sd;

    const int tid = threadIdx.x;
    const int lane = tid & 63;
    const int wv = tid >> 6;
    const int n = blockIdx.x;
    const int lrow = lane & 15;
    const int lq = lane >> 4;

    // ---- P0: stage x (8 px/thread -> one aligned b128 write) + zero pads ----
    {
        const float4* xv = (const float4*)(x + (size_t)n * 4096);
        #pragma unroll
        for (int i = 0; i < 2; ++i) {
            int u = tid + 256 * i;
            int y = u >> 3, c8 = u & 7;
            float4 va = xv[y * 16 + c8 * 2];
            float4 vb = xv[y * 16 + c8 * 2 + 1];
            uint4 st;
            st.x = cvtpk(va.x, va.y); st.y = cvtpk(va.z, va.w);
            st.z = cvtpk(vb.x, vb.y); st.w = cvtpk(vb.z, vb.w);
            *(uint4*)&sd[(y + 2) * 40 + 4 + c8 * 4] = st;
        }
        if (tid < 68)       { int r = tid / 34, c = tid % 34; sd[r * 40 + c + 3] = 0u; }
        else if (tid < 136) { int u = tid - 68; int r = 66 + u / 34, c = u % 34; sd[r * 40 + c + 3] = 0u; }
        if (tid < 128) { int r = 2 + (tid & 63); sd[r * 40 + ((tid >> 6) ? 36 : 3)] = 0u; }
        if (tid < 132) {
            int p;
            if (tid < 34) p = tid;
            else if (tid < 68) p = 33 * 34 + (tid - 34);
            else { int r = 1 + ((tid - 68) & 31); int side = (tid - 68) >> 5; p = r * 34 + side * 33; }
            h1p4[swz(p)] = (uint4){0u, 0u, 0u, 0u};
        }
    }
    __syncthreads();   // B1

    // ---- conv1 (swapped, hi only) ----
    {
        bf16x8 wf0 = __builtin_bit_cast(bf16x8, *(const uint4*)(cpack + W1OFF + lane * 8));
        bf16x8 wf2 = __builtin_bit_cast(bf16x8, *(const uint4*)(cpack + W1OFF + 2 * 512 + lane * 8));
        float s1v[4], sh1v[4];
        #pragma unroll
        for (int r = 0; r < 4; ++r) {
            int oc = (4 * lq + r) & 7;
            s1v[r] = bn1g[oc] * rsqrtf(bn1v[oc] + 1e-5f);
            sh1v[r] = (c1b[oc] - bn1m[oc]) * s1v[r] + bn1b[oc];
        }
        #pragma unroll 4
        for (int t = 0; t < 16; ++t) {
            int oy = wv * 8 + (t >> 1), h = t & 1;
            int a1 = (2 * oy + lq) * 40 + 16 * h + lrow + 3;
            u2a4 r1 = *(const u2a4*)&sd[a1];
            uint4 d1; d1.x = r1.x; d1.y = r1.y; d1.z = sd[a1 + 2]; d1.w = 0u;
            int a2 = (2 * oy + 4) * 40 + 16 * h + lrow + 3;
            u2a4 r2 = *(const u2a4*)&sd[a2];
            uint4 d2; d2.x = r2.x; d2.y = r2.y; d2.z = sd[a2 + 2]; d2.w = 0u;
            f32x4 acc = {0.f, 0.f, 0.f, 0.f};
            acc = __builtin_amdgcn_mfma_f32_16x16x32_bf16(wf0, __builtin_bit_cast(bf16x8, d1), acc, 0, 0, 0);
            acc = __builtin_amdgcn_mfma_f32_16x16x32_bf16(wf2, __builtin_bit_cast(bf16x8, d2), acc, 0, 0, 0);
            if (lq < 2) {
                unsigned int u0 = cvtpk(fmaxf(fmaf(acc[0], s1v[0], sh1v[0]), 0.f),
                                        fmaxf(fmaf(acc[1], s1v[1], sh1v[1]), 0.f));
                unsigned int u1 = cvtpk(fmaxf(fmaf(acc[2], s1v[2], sh1v[2]), 0.f),
                                        fmaxf(fmaf(acc[3], s1v[3], sh1v[3]), 0.f));
                int p = (oy + 1) * 34 + 16 * h + lrow + 1;
                uint2 wr; wr.x = u0; wr.y = u1;
                *(uint2*)((char*)h1p4 + swz(p) * 16 + 8 * lq) = wr;
            }
        }
    }
    __syncthreads();   // B2

    // ---- P2: zero h2p ring (planar) + conv2 (swapped, hi only) ----
    {
        if (tid < 136) {
            int pp = tid >> 1, plane = tid & 1;
            int p;
            if (pp < 18) p = pp;
            else if (pp < 36) p = 17 * 18 + (pp - 18);
            else { int r = 1 + ((pp - 36) & 15); int side = (pp - 36) >> 4; p = r * 18 + side * 17; }
            sbuf4[plane * 324 + p] = (uint4){0u, 0u, 0u, 0u};
        }
        bf16x8 w2f[3];
        #pragma unroll
        for (int ky = 0; ky < 3; ++ky)
            w2f[ky] = __builtin_bit_cast(bf16x8,
                *(const uint4*)(cpack + W2OFF + (ky * 2) * 512 + lane * 8));
        float s2v[4], sh2v[4];
        #pragma unroll
        for (int r = 0; r < 4; ++r) {
            int oc = 4 * lq + r;
            s2v[r] = bn2g[oc] * rsqrtf(bn2v[oc] + 1e-5f);
            sh2v[r] = (c2b[oc] - bn2m[oc]) * s2v[r] + bn2b[oc];
        }
        int lqe = (lq == 3) ? 0 : lq;
        #pragma unroll
        for (int t = 0; t < 4; ++t) {
            int oy = 4 * wv + t;
            f32x4 acc = {0.f, 0.f, 0.f, 0.f};
            #pragma unroll
            for (int ky = 0; ky < 3; ++ky) {
                int iy = 2 * oy + ky;
                int p = iy * 34 + 2 * lrow + lqe;
                bf16x8 b = __builtin_bit_cast(bf16x8, h1p4[swz(p)]);
                acc = __builtin_amdgcn_mfma_f32_16x16x32_bf16(w2f[ky], b, acc, 0, 0, 0);
            }
            unsigned int u0 = cvtpk(fmaxf(fmaf(acc[0], s2v[0], sh2v[0]), 0.f),
                                    fmaxf(fmaf(acc[1], s2v[1], sh2v[1]), 0.f));
            unsigned int u1 = cvtpk(fmaxf(fmaf(acc[2], s2v[2], sh2v[2]), 0.f),
                                    fmaxf(fmaf(acc[3], s2v[3], sh2v[3]), 0.f));
            int p = (oy + 1) * 18 + lrow + 1;
            uint2 wr; wr.x = u0; wr.y = u1;
            *(uint2*)((char*)sbuf4 + ((lq >> 1) * 324 + p) * 16 + 8 * (lq & 1)) = wr;
        }
    }
    __syncthreads();   // B3

    // ---- conv3 (32x32x16, hi only) + BN/ReLU + pool ----
    {
        f32x16 accA = {0.f}, accB = {0.f};
        const int row = lane & 31;
        const int khalf = lane >> 5;
        const int kbase = khalf * 324;
        #pragma unroll
        for (int ky = 0; ky < 3; ++ky)
            #pragma unroll
            for (int kx = 0; kx < 3; ++kx) {
                int fb = (ky * 3 + kx) * 2;
                bf16x8 bh = __builtin_bit_cast(bf16x8, *(const uint4*)(cpack + W3OFF + fb * 512 + lane * 8));
                {
                    int pix = (4 * wv + 0 + (row >> 4) + ky) * 18 + (row & 15) + kx;
                    bf16x8 a = __builtin_bit_cast(bf16x8, sbuf4[kbase + pix]);
                    accA = __builtin_amdgcn_mfma_f32_32x32x16_bf16(a, bh, accA, 0, 0, 0);
                }
                {
                    int pix = (4 * wv + 2 + (row >> 4) + ky) * 18 + (row & 15) + kx;
                    bf16x8 a = __builtin_bit_cast(bf16x8, sbuf4[kbase + pix]);
                    accB = __builtin_amdgcn_mfma_f32_32x32x16_bf16(a, bh, accB, 0, 0, 0);
                }
            }
        int oc = lane & 31;
        float s3 = bn3g[oc] * rsqrtf(bn3v[oc] + 1e-5f);
        float sh3 = (c3b[oc] - bn3m[oc]) * s3 + bn3b[oc];
        float pool0 = 0.f, pool1 = 0.f;
        #pragma unroll
        for (int r = 0; r < 16; ++r) {
            float va = fmaxf(fmaf(accA[r], s3, sh3), 0.f);
            float vb = fmaxf(fmaf(accB[r], s3, sh3), 0.f);
            if (((r >> 2) & 1) == 0) { pool0 += va + vb; } else { pool1 += va + vb; }
        }
        int base = n * 512 + oc * 16 + wv * 4 + khalf;
        pooled_bf[base]     = (unsigned short)cvtpk(pool0 * (1.f / 16.f), 0.f);
        pooled_bf[base + 2] = (unsigned short)cvtpk(pool1 * (1.f / 16.f), 0.f);
    }
}

// ---------------------------------------------------------------------------
// Head: FC1 -> FC2 -> L2norm+qsim -> tail MLP. 16 samples/block, 512 blocks,
// 512 threads (8 waves): FC1 3 frags/wave, FC2 2 frags/wave, qsim 2 its/wave.
// 36 KB LDS -> 4 blocks/CU = 100% wave-slot occupancy. Staging exact (1024 u4).
// ---------------------------------------------------------------------------
__global__ __launch_bounds__(512) void head_kernel(
    const unsigned short* __restrict__ pooled_bf,
    const unsigned short* __restrict__ fpack1,
    const unsigned short* __restrict__ fpack2,
    const float* __restrict__ f1b, const float* __restrict__ f2b,
    const float* __restrict__ angtab,
    const float* __restrict__ w1, const float* __restrict__ b1,
    const float* __restrict__ cg, const float* __restrict__ cb,
    const float* __restrict__ cm, const float* __restrict__ cv,
    const float* __restrict__ w2, const float* __restrict__ b2,
    const float* __restrict__ w3, const float* __restrict__ b3,
    const float* __restrict__ w4, const float* __restrict__ b4,
    float* __restrict__ out)
{
    __shared__ __align__(16) unsigned short As[8192];   // [16][512]
    __shared__ __align__(16) unsigned short h1[6144];   // [16][384]
    __shared__ __align__(16) unsigned short h2[4096];   // [16][256]

    const int tid = threadIdx.x;
    const int lane = tid & 63;
    const int w = tid >> 6;           // wave 0..7
    const int lr = lane & 15;
    const int lq = lane >> 4;
    const int m0 = blockIdx.x * 16;

    // ---- stage pooled[m0..m0+15][0..511]: exactly 1024 uint4 ----
    {
        const uint4* src = (const uint4*)(pooled_bf + (size_t)m0 * 512);
        #pragma unroll
        for (int i = 0; i < 2; ++i) {
            int q = i * 512 + tid;           // 0..1023; row=q>>6, kc=q&63
            uint4 v = src[q];
            int row = q >> 6, kc = q & 63;
            int byte = (row * 1024 + 16 * kc) ^ ((row & 7) << 4);
            *(uint4*)((char*)As + byte) = v;
        }
    }
    __syncthreads();   // B1

    // ---- FC1: wave w covers n in [48w, 48w+48), 3 frags; K=512=16 ks ----
    {
        f32x4 acc[3];
        #pragma unroll
        for (int i = 0; i < 3; ++i) acc[i] = (f32x4){0.f, 0.f, 0.f, 0.f};
        for (int ks = 0; ks < 16; ++ks) {
            int byte = (lr * 1024 + 16 * (ks * 4 + lq)) ^ ((lr & 7) << 4);
            bf16x8 act = __builtin_bit_cast(bf16x8, *(const uint4*)((char*)As + byte));
            #pragma unroll
            for (int nf = 0; nf < 3; ++nf) {
                int nb = 3 * w + nf;
                bf16x8 wf = __builtin_bit_cast(bf16x8,
                    *(const uint4*)(fpack1 + (size_t)(nb * 16 + ks) * 512 + lane * 8));
                acc[nf] = __builtin_amdgcn_mfma_f32_16x16x32_bf16(wf, act, acc[nf], 0, 0, 0);
            }
        }
        #pragma unroll
        for (int nf = 0; nf < 3; ++nf) {
            int n0 = 48 * w + 16 * nf + 4 * lq;
            float4 bb = *(const float4*)(f1b + n0);
            unsigned int u0 = cvtpk(relu_(acc[nf][0] + bb.x), relu_(acc[nf][1] + bb.y));
            unsigned int u1 = cvtpk(relu_(acc[nf][2] + bb.z), relu_(acc[nf][3] + bb.w));
            int byte = (lr * 768 + 2 * n0) ^ ((lr & 7) << 4);
            uint2 wr; wr.x = u0; wr.y = u1;
            *(uint2*)((char*)h1 + byte) = wr;
        }
    }
    __syncthreads();   // B2

    // ---- FC2: wave w covers n in [32w, 32w+32), 2 frags; K=384=12 ks ----
    {
        f32x4 acc[2];
        #pragma unroll
        for (int i = 0; i < 2; ++i) acc[i] = (f32x4){0.f, 0.f, 0.f, 0.f};
        for (int ks = 0; ks < 12; ++ks) {
            int byte = (lr * 768 + 16 * (ks * 4 + lq)) ^ ((lr & 7) << 4);
            bf16x8 act = __builtin_bit_cast(bf16x8, *(const uint4*)((char*)h1 + byte));
            #pragma unroll
            for (int nf = 0; nf < 2; ++nf) {
                int nb = 2 * w + nf;
                bf16x8 wf = __builtin_bit_cast(bf16x8,
                    *(const uint4*)(fpack2 + (size_t)(nb * 12 + ks) * 512 + lane * 8));
                acc[nf] = __builtin_amdgcn_mfma_f32_16x16x32_bf16(wf, act, acc[nf], 0, 0, 0);
            }
        }
        #pragma unroll
        for (int nf = 0; nf < 2; ++nf) {
            int n0 = 32 * w + 16 * nf + 4 * lq;
            float4 bb = *(const float4*)(f2b + n0);
            unsigned int u0 = cvtpk(relu_(acc[nf][0] + bb.x), relu_(acc[nf][1] + bb.y));
            unsigned int u1 = cvtpk(relu_(acc[nf][2] + bb.z), relu_(acc[nf][3] + bb.w));
            int byte = (lr * 512 + 2 * n0) ^ ((lr & 7) << 3);
            uint2 wr; wr.x = u0; wr.y = u1;
            *(uint2*)((char*)h2 + byte) = wr;
        }
    }
    __syncthreads();   // B3

    // ---- qsim + tail, 2 samples per wave ----
    const int csrc = lane ^ ((lane >> 1) & 31);
    for (int it = 0; it < 2; ++it) {
        int m = w * 2 + it;
        int byte = (m * 512 + 8 * lane) ^ ((m & 7) << 3);
        uint2 fv = *(const uint2*)((char*)h2 + byte);
        float a0 = bf2f((unsigned short)(fv.x & 0xffff));
        float a1 = bf2f((unsigned short)(fv.x >> 16));
        float a2 = bf2f((unsigned short)(fv.y & 0xffff));
        float a3 = bf2f((unsigned short)(fv.y >> 16));

        float ss = a0 * a0 + a1 * a1 + a2 * a2 + a3 * a3;
        #pragma unroll
        for (int mm = 32; mm; mm >>= 1) ss += __shfl_xor(ss, mm);
        float inv = 1.f / fmaxf(sqrtf(ss), 1e-12f);
        a0 *= inv; a1 *= inv; a2 *= inv; a3 *= inv;

        for (int l = 0; l < 7; ++l) {
            #pragma unroll
            for (int q = 0; q < 6; ++q) {
                float cs = angtab[(l * 8 + q) * 2], sn = angtab[(l * 8 + q) * 2 + 1];
                int mask = 32 >> q;
                float sg = (lane & mask) ? sn : -sn;
                float b0 = __shfl_xor(a0, mask), b1v = __shfl_xor(a1, mask);
                float b2v = __shfl_xor(a2, mask), b3v = __shfl_xor(a3, mask);
                a0 = fmaf(sg, b0, cs * a0); a1 = fmaf(sg, b1v, cs * a1);
                a2 = fmaf(sg, b2v, cs * a2); a3 = fmaf(sg, b3v, cs * a3);
            }
            {
                float cs = angtab[(l * 8 + 6) * 2], sn = angtab[(l * 8 + 6) * 2 + 1];
                float n0 = cs * a0 - sn * a2, n2 = fmaf(sn, a0, cs * a2);
                float n1 = cs * a1 - sn * a3, n3 = fmaf(sn, a1, cs * a3);
                a0 = n0; a1 = n1; a2 = n2; a3 = n3;
            }
            {
                float cs = angtab[(l * 8 + 7) * 2], sn = angtab[(l * 8 + 7) * 2 + 1];
                float n0 = cs * a0 - sn * a1, n1 = fmaf(sn, a0, cs * a1);
                float n2 = cs * a2 - sn * a3, n3 = fmaf(sn, a2, cs * a3);
                a0 = n0; a1 = n1; a2 = n2; a3 = n3;
            }
            a0 = __shfl(a0, csrc); a1 = __shfl(a1, csrc);
            a2 = __shfl(a2, csrc); a3 = __shfl(a3, csrc);
            {
                bool f = (lane & 1);
                float n0 = f ? a2 : a0, n2 = f ? a0 : a2;
                float n1 = f ? a3 : a1, n3 = f ? a1 : a3;
                a0 = n0; a1 = n1; a2 = n2; a3 = n3;
            }
            { float t = a2; a2 = a3; a3 = t; }
        }

        float part = a0 * a0 + a1 * a1 + a2 * a2 + a3 * a3;
        part = (lane & 32) ? -part : part;
        #pragma unroll
        for (int mm = 32; mm; mm >>= 1) part += __shfl_xor(part, mm);
        float qv = part;

        float z = fmaxf(fmaf(qv, w1[lane], b1[lane]), 0.f);
        z = fmaf(z - cm[lane], cg[lane] * rsqrtf(cv[lane] + 1e-5f), cb[lane]);
        {
            int j = lane & 31, hb = lane & 32;
            float acc = 0.f;
            #pragma unroll
            for (int t = 0; t < 32; ++t)
                acc = fmaf(w2[j * 64 + hb + t], __shfl(z, hb + t), acc);
            acc += __shfl_xor(acc, 32);
            z = fmaxf(acc + b2[j], 0.f);
        }
        {
            int j3 = lane & 15, qh = (lane >> 4) & 3;
            float p = 0.f;
            #pragma unroll
            for (int t = 0; t < 8; ++t)
                p = fmaf(w3[j3 * 32 + 8 * qh + t], __shfl(z, 8 * qh + t), p);
            p += __shfl_xor(p, 16);
            p += __shfl_xor(p, 32);
            z = fmaxf(p + b3[j3], 0.f);
        }
        {
            float t4 = w4[lane & 15] * z;
            t4 += __shfl_xor(t4, 1); t4 += __shfl_xor(t4, 2);
            t4 += __shfl_xor(t4, 4); t4 += __shfl_xor(t4, 8);
            float o = t4 + b4[0];
            if (lane == 0) out[m0 + m] = 1.f / (1.f + expf(-o));
        }
    }
}

// ---------------------------------------------------------------------------
extern "C" void kernel_launch(void* const* d_in, const int* in_sizes, int n_in,
                              void* d_out, int out_size, void* d_ws, size_t ws_size,
                              hipStream_t stream)
{
    const float* x    = (const float*)d_in[0];
    const float* c1w  = (const float*)d_in[1];
    const float* c1b  = (const float*)d_in[2];
    const float* bn1g = (const float*)d_in[3];
    const float* bn1b = (const float*)d_in[4];
    const float* bn1m = (const float*)d_in[5];
    const float* bn1v = (const float*)d_in[6];
    const float* c2w  = (const float*)d_in[7];
    const float* c2b  = (const float*)d_in[8];
    const float* bn2g = (const float*)d_in[9];
    const float* bn2b = (const float*)d_in[10];
    const float* bn2m = (const float*)d_in[11];
    const float* bn2v = (const float*)d_in[12];
    const float* c3w  = (const float*)d_in[13];
    const float* c3b  = (const float*)d_in[14];
    const float* bn3g = (const float*)d_in[15];
    const float* bn3b = (const float*)d_in[16];
    const float* bn3m = (const float*)d_in[17];
    const float* bn3v = (const float*)d_in[18];
    const float* f1w  = (const float*)d_in[19];
    const float* f1b  = (const float*)d_in[20];
    const float* f2w  = (const float*)d_in[21];
    const float* f2b  = (const float*)d_in[22];
    const float* qw   = (const float*)d_in[23];
    const float* w1   = (const float*)d_in[24];
    const float* b1   = (const float*)d_in[25];
    const float* cg   = (const float*)d_in[26];
    const float* cb   = (const float*)d_in[27];
    const float* cm   = (const float*)d_in[28];
    const float* cv   = (const float*)d_in[29];
    const float* w2   = (const float*)d_in[30];
    const float* b2   = (const float*)d_in[31];
    const float* w3   = (const float*)d_in[32];
    const float* b3   = (const float*)d_in[33];
    const float* w4   = (const float*)d_in[34];
    const float* b4   = (const float*)d_in[35];

    unsigned short* ws = (unsigned short*)d_ws;
    unsigned short* pooled_bf = ws;                              // 8192*512 ush
    unsigned short* cpack     = pooled_bf + (size_t)BATCH * 512;
    unsigned short* fpack1    = cpack + CPACK_TOTAL;
    unsigned short* fpack2    = fpack1 + FC1_TOTAL;
    float*          angtab    = (float*)(fpack2 + FC2_TOTAL);

    prepack_kernel<<<(PREP_TOTAL + 255) / 256, 256, 0, stream>>>(
        c1w, c2w, c3w, f1w, f2w, qw, cpack, fpack1, fpack2, angtab);

    fused_cnn_mfma<<<BATCH, 256, 0, stream>>>(
        x, c1b, bn1g, bn1b, bn1m, bn1v,
        c2b, bn2g, bn2b, bn2m, bn2v,
        c3b, bn3g, bn3b, bn3m, bn3v, cpack, pooled_bf);

    head_kernel<<<BATCH / 16, 512, 0, stream>>>(
        pooled_bf, fpack1, fpack2, f1b, f2b, angtab,
        w1, b1, cg, cb, cm, cv, w2, b2, w3, b3, w4, b4, (float*)d_out);
}